// Round 1
// baseline (6437.412 us; speedup 1.0000x reference)
//
#include <hip/hip_runtime.h>
#include <math.h>

#define KC 16
#define TILE 128

// ---------------- reduction helpers (256 threads = 4 waves) ----------------
__device__ __forceinline__ float block_sum256(float v, float* red) {
  #pragma unroll
  for (int o = 32; o > 0; o >>= 1) v += __shfl_down(v, o, 64);
  __syncthreads();                       // protect red[] reuse
  if ((threadIdx.x & 63) == 0) red[threadIdx.x >> 6] = v;
  __syncthreads();
  return red[0] + red[1] + red[2] + red[3];
}

__device__ __forceinline__ float block_max256(float v, float* red) {
  #pragma unroll
  for (int o = 32; o > 0; o >>= 1) v = fmaxf(v, __shfl_down(v, o, 64));
  __syncthreads();
  if ((threadIdx.x & 63) == 0) red[threadIdx.x >> 6] = v;
  __syncthreads();
  return fmaxf(fmaxf(red[0], red[1]), fmaxf(red[2], red[3]));
}

// ---------------- GEMM (K-outer x K-outer):
// C[n,m] = scale * sum_k A[k*lda + n] * B[k*ldb + m] + bias[n]
// A:[K,Nc], B:[K,M], C:[Nc,M]. M is an exact multiple of TILE; Nc, K guarded.
__global__ __launch_bounds__(256) void gemm_ktn(
    const float* __restrict__ A, const float* __restrict__ B,
    float* __restrict__ C, const float* __restrict__ bias,
    int K, int Nc, int M, int lda, int ldb, int ldc, float scale)
{
  __shared__ __align__(16) float As[KC][TILE + 4];
  __shared__ __align__(16) float Bs[KC][TILE + 4];
  const int t  = threadIdx.x;
  const int m0 = blockIdx.x * TILE;
  const int n0 = blockIdx.y * TILE;
  const int tx = t & 15;          // -> m (contiguous in C)
  const int ty = t >> 4;          // -> n
  const int kk = t >> 4;          // staging row
  const int sc = (t & 15) * 8;    // staging col

  float acc[8][8];
  #pragma unroll
  for (int i = 0; i < 8; ++i)
    #pragma unroll
    for (int j = 0; j < 8; ++j) acc[i][j] = 0.f;

  for (int k0 = 0; k0 < K; k0 += KC) {
    float a[8], b[8];
    const int kg = k0 + kk;
    if (kg < K) {
      const int nb = n0 + sc;
      const float* Ap = A + (size_t)kg * lda + nb;
      if (nb + 7 < Nc) {
        *(float4*)&a[0] = *(const float4*)(Ap);
        *(float4*)&a[4] = *(const float4*)(Ap + 4);
      } else {
        #pragma unroll
        for (int e = 0; e < 8; ++e) a[e] = (nb + e < Nc) ? Ap[e] : 0.f;
      }
      const float* Bp = B + (size_t)kg * ldb + m0 + sc;
      *(float4*)&b[0] = *(const float4*)(Bp);
      *(float4*)&b[4] = *(const float4*)(Bp + 4);
    } else {
      #pragma unroll
      for (int e = 0; e < 8; ++e) { a[e] = 0.f; b[e] = 0.f; }
    }
    __syncthreads();
    *(float4*)&As[kk][sc]     = *(float4*)&a[0];
    *(float4*)&As[kk][sc + 4] = *(float4*)&a[4];
    *(float4*)&Bs[kk][sc]     = *(float4*)&b[0];
    *(float4*)&Bs[kk][sc + 4] = *(float4*)&b[4];
    __syncthreads();
    #pragma unroll
    for (int kq = 0; kq < KC; ++kq) {
      float av[8], bv[8];
      *(float4*)&av[0] = *(const float4*)&As[kq][ty * 8];
      *(float4*)&av[4] = *(const float4*)&As[kq][ty * 8 + 4];
      *(float4*)&bv[0] = *(const float4*)&Bs[kq][tx * 8];
      *(float4*)&bv[4] = *(const float4*)&Bs[kq][tx * 8 + 4];
      #pragma unroll
      for (int i = 0; i < 8; ++i)
        #pragma unroll
        for (int j = 0; j < 8; ++j) acc[i][j] += av[i] * bv[j];
    }
  }
  #pragma unroll
  for (int i = 0; i < 8; ++i) {
    const int n = n0 + ty * 8 + i;
    if (n < Nc) {
      const float bb = bias ? bias[n] : 0.f;
      float o0[8];
      #pragma unroll
      for (int j = 0; j < 8; ++j) o0[j] = acc[i][j] * scale + bb;
      float* Cp = C + (size_t)n * ldc + m0 + tx * 8;
      *(float4*)(Cp)     = *(float4*)&o0[0];
      *(float4*)(Cp + 4) = *(float4*)&o0[4];
    }
  }
}

// ---------------- GEMM (row . row):
// C[m,n] (+)= sum_k A[m*lda + k] * B[n*ldb + k]. K%16==0, N exact, M guarded.
__global__ __launch_bounds__(256) void gemm_nt(
    const float* __restrict__ A, const float* __restrict__ B,
    float* __restrict__ C,
    int M, int N, int K, int lda, int ldb, int ldc,
    int accumulate, int do_relu)
{
  __shared__ __align__(16) float As[KC][TILE + 4];
  __shared__ __align__(16) float Bs[KC][TILE + 4];
  const int t  = threadIdx.x;
  const int n0 = blockIdx.x * TILE;
  const int m0 = blockIdx.y * TILE;
  const int tx = t & 15;          // -> n (contiguous in C)
  const int ty = t >> 4;          // -> m
  const int srow = t >> 1;        // staging row in tile (0..127)
  const int ke = (t & 1) * 8;     // staging k offset

  float acc[8][8];
  #pragma unroll
  for (int i = 0; i < 8; ++i)
    #pragma unroll
    for (int j = 0; j < 8; ++j) acc[i][j] = 0.f;

  for (int k0 = 0; k0 < K; k0 += KC) {
    float a[8], b[8];
    const int ma = m0 + srow;
    if (ma < M) {
      const float* Ap = A + (size_t)ma * lda + k0 + ke;
      *(float4*)&a[0] = *(const float4*)(Ap);
      *(float4*)&a[4] = *(const float4*)(Ap + 4);
    } else {
      #pragma unroll
      for (int e = 0; e < 8; ++e) a[e] = 0.f;
    }
    const float* Bp = B + (size_t)(n0 + srow) * ldb + k0 + ke;
    *(float4*)&b[0] = *(const float4*)(Bp);
    *(float4*)&b[4] = *(const float4*)(Bp + 4);
    __syncthreads();
    #pragma unroll
    for (int e = 0; e < 8; ++e) { As[ke + e][srow] = a[e]; Bs[ke + e][srow] = b[e]; }
    __syncthreads();
    #pragma unroll
    for (int kq = 0; kq < KC; ++kq) {
      float av[8], bv[8];
      *(float4*)&av[0] = *(const float4*)&As[kq][ty * 8];
      *(float4*)&av[4] = *(const float4*)&As[kq][ty * 8 + 4];
      *(float4*)&bv[0] = *(const float4*)&Bs[kq][tx * 8];
      *(float4*)&bv[4] = *(const float4*)&Bs[kq][tx * 8 + 4];
      #pragma unroll
      for (int i = 0; i < 8; ++i)
        #pragma unroll
        for (int j = 0; j < 8; ++j) acc[i][j] += av[i] * bv[j];
    }
  }
  #pragma unroll
  for (int i = 0; i < 8; ++i) {
    const int m = m0 + ty * 8 + i;
    if (m < M) {
      float* Cp = C + (size_t)m * ldc + n0 + tx * 8;
      float o0[8];
      #pragma unroll
      for (int j = 0; j < 8; ++j) o0[j] = acc[i][j];
      if (accumulate) {
        float old[8];
        *(float4*)&old[0] = *(const float4*)(Cp);
        *(float4*)&old[4] = *(const float4*)(Cp + 4);
        #pragma unroll
        for (int j = 0; j < 8; ++j) o0[j] += old[j];
      }
      if (do_relu) {
        #pragma unroll
        for (int j = 0; j < 8; ++j) o0[j] = fmaxf(o0[j], 0.f);
      }
      *(float4*)(Cp)     = *(float4*)&o0[0];
      *(float4*)(Cp + 4) = *(float4*)&o0[4];
    }
  }
}

// ---------------- row softmax, in place, 4096 cols ----------------
__global__ __launch_bounds__(256) void softmax_rows(float* __restrict__ S)
{
  __shared__ float red[4];
  const int t = threadIdx.x;
  float* p = S + (size_t)blockIdx.x * 4096;
  float v[16];
  float mx = -3.4e38f;
  #pragma unroll
  for (int e = 0; e < 4; ++e) {
    *(float4*)&v[e * 4] = *(const float4*)&p[t * 4 + 1024 * e];
    #pragma unroll
    for (int q = 0; q < 4; ++q) mx = fmaxf(mx, v[e * 4 + q]);
  }
  mx = block_max256(mx, red);
  float sum = 0.f;
  #pragma unroll
  for (int e = 0; e < 16; ++e) { v[e] = __expf(v[e] - mx); sum += v[e]; }
  sum = block_sum256(sum, red);
  const float inv = 1.f / sum;
  #pragma unroll
  for (int e = 0; e < 4; ++e) {
    float o0[4];
    #pragma unroll
    for (int q = 0; q < 4; ++q) o0[q] = v[e * 4 + q] * inv;
    *(float4*)&p[t * 4 + 1024 * e] = *(float4*)&o0[0];
  }
}

// ---------------- GraphNorm over 4096 cols per row (feature-major), optional
// fused row-L2-normalize. In-place safe (each element read+written by one thread).
template<bool L2NORM>
__global__ __launch_bounds__(256) void graph_norm_rows(
    const float* __restrict__ X, float* __restrict__ Y,
    const float* __restrict__ w, const float* __restrict__ b,
    const float* __restrict__ ms)
{
  __shared__ float red[4];
  const int t = threadIdx.x;
  const int row = blockIdx.x;
  const float* x = X + (size_t)row * 4096;
  float v[16];
  float s = 0.f;
  #pragma unroll
  for (int e = 0; e < 4; ++e) {
    *(float4*)&v[e * 4] = *(const float4*)&x[t * 4 + 1024 * e];
    #pragma unroll
    for (int q = 0; q < 4; ++q) s += v[e * 4 + q];
  }
  const float mean = block_sum256(s, red) * (1.f / 4096.f);
  const float sub = mean * ms[row];
  float s2 = 0.f;
  #pragma unroll
  for (int e = 0; e < 16; ++e) { v[e] -= sub; s2 += v[e] * v[e]; }
  const float var = block_sum256(s2, red) * (1.f / 4096.f);
  const float scl = rsqrtf(var + 1e-5f) * w[row];
  const float bb = b[row];
  #pragma unroll
  for (int e = 0; e < 16; ++e) v[e] = v[e] * scl + bb;
  float osc = 1.f;
  if (L2NORM) {
    float s3 = 0.f;
    #pragma unroll
    for (int e = 0; e < 16; ++e) s3 += v[e] * v[e];
    osc = rsqrtf(block_sum256(s3, red));
  }
  float* y = Y + (size_t)row * 4096;
  #pragma unroll
  for (int e = 0; e < 4; ++e) {
    float o0[4];
    #pragma unroll
    for (int q = 0; q < 4; ++q) o0[q] = v[e * 4 + q] * osc;
    *(float4*)&y[t * 4 + 1024 * e] = *(float4*)&o0[0];
  }
}

extern "C" void kernel_launch(void* const* d_in, const int* in_sizes, int n_in,
                              void* d_out, int out_size, void* d_ws, size_t ws_size,
                              hipStream_t stream)
{
  (void)in_sizes; (void)n_in; (void)out_size; (void)ws_size;
  const float* lr_x = (const float*)d_in[0];
  const float* Wq1 = (const float*)d_in[1];  const float* bq1 = (const float*)d_in[2];
  const float* Wk1 = (const float*)d_in[3];  const float* bk1 = (const float*)d_in[4];
  const float* Wv1 = (const float*)d_in[5];  const float* bv1 = (const float*)d_in[6];
  const float* Ws1 = (const float*)d_in[7];  const float* bs1 = (const float*)d_in[8];
  const float* gn1w = (const float*)d_in[9]; const float* gn1b = (const float*)d_in[10];
  const float* gn1ms = (const float*)d_in[11];
  const float* Wq2 = (const float*)d_in[12]; const float* bq2 = (const float*)d_in[13];
  const float* Wk2 = (const float*)d_in[14]; const float* bk2 = (const float*)d_in[15];
  const float* Wv2 = (const float*)d_in[16]; const float* bv2 = (const float*)d_in[17];
  const float* Ws2 = (const float*)d_in[18]; const float* bs2 = (const float*)d_in[19];
  const float* gn2w = (const float*)d_in[20]; const float* gn2b = (const float*)d_in[21];
  const float* gn2ms = (const float*)d_in[22];

  // workspace carve (fp32), all feature-major [D, 4096]:
  float* ws   = (float*)d_ws;
  float* q1T  = ws;                           // [200 ,4096]
  float* k1T  = q1T  + (size_t)200  * 4096;   // [200 ,4096]
  float* v1T  = k1T  + (size_t)200  * 4096;   // [200 ,4096]
  float* s1T  = v1T  + (size_t)200  * 4096;   // [200 ,4096] skip, then += attn
  float* h1nT = s1T  + (size_t)200  * 4096;   // [200 ,4096]
  float* q2hT = h1nT + (size_t)200  * 4096;   // [512 ,4096] per-head
  float* k2hT = q2hT + (size_t)512  * 4096;   // [512 ,4096]
  float* v2hT = k2hT + (size_t)512  * 4096;   // [512 ,4096]
  float* s2T  = v2hT + (size_t)512  * 4096;   // [2048,4096] skip, then += attn, then gn2+L2 in place
  float* scores = s2T + (size_t)2048 * 4096;  // [4096,4096] reused per head
  // total: 35,553,280 floats = 142.2 MB

  const dim3 blk(256, 1, 1);
  const float sc1 = 0.14142135623730951f;  // 1/sqrt(50)
  const float sc2 = 0.04419417382415922f;  // 1/sqrt(512)

  // ---- layer 1 projections: [200,4096] = Wt[512,200]^T . lr_x[512,4096]
  gemm_ktn<<<dim3(32, 2), blk, 0, stream>>>(Wq1, lr_x, q1T, bq1, 512, 200, 4096, 200, 4096, 4096, 1.f);
  gemm_ktn<<<dim3(32, 2), blk, 0, stream>>>(Wk1, lr_x, k1T, bk1, 512, 200, 4096, 200, 4096, 4096, 1.f);
  gemm_ktn<<<dim3(32, 2), blk, 0, stream>>>(Wv1, lr_x, v1T, bv1, 512, 200, 4096, 200, 4096, 4096, 1.f);
  gemm_ktn<<<dim3(32, 2), blk, 0, stream>>>(Ws1, lr_x, s1T, bs1, 512, 200, 4096, 200, 4096, 4096, 1.f);

  // ---- attention 1 (C=50) per head: scores -> softmax -> PV accumulated into skip
  for (int h = 0; h < 4; ++h) {
    const float* qh = q1T + (size_t)h * 50 * 4096;
    const float* kh = k1T + (size_t)h * 50 * 4096;
    const float* vh = v1T + (size_t)h * 50 * 4096;
    gemm_ktn<<<dim3(32, 32), blk, 0, stream>>>(qh, kh, scores, nullptr, 50, 4096, 4096, 4096, 4096, 4096, sc1);
    softmax_rows<<<dim3(4096), blk, 0, stream>>>(scores);
    gemm_nt<<<dim3(32, 1), blk, 0, stream>>>(vh, scores, s1T + (size_t)h * 50 * 4096,
                                             50, 4096, 4096, 4096, 4096, 4096, 1, 0);
  }
  graph_norm_rows<false><<<dim3(200), blk, 0, stream>>>(s1T, h1nT, gn1w, gn1b, gn1ms);

  // ---- layer 2 skip: s2T[2048,4096] = Ws2^T . h1n
  gemm_ktn<<<dim3(32, 16), blk, 0, stream>>>(Ws2, h1nT, s2T, bs2, 200, 2048, 4096, 2048, 4096, 4096, 1.f);

  // ---- attention 2 (C=512) per head
  for (int h = 0; h < 4; ++h) {
    gemm_ktn<<<dim3(32, 4), blk, 0, stream>>>(Wq2 + h * 512, h1nT, q2hT, bq2 + h * 512,
                                              200, 512, 4096, 2048, 4096, 4096, 1.f);
    gemm_ktn<<<dim3(32, 4), blk, 0, stream>>>(Wk2 + h * 512, h1nT, k2hT, bk2 + h * 512,
                                              200, 512, 4096, 2048, 4096, 4096, 1.f);
    gemm_ktn<<<dim3(32, 4), blk, 0, stream>>>(Wv2 + h * 512, h1nT, v2hT, bv2 + h * 512,
                                              200, 512, 4096, 2048, 4096, 4096, 1.f);
    gemm_ktn<<<dim3(32, 32), blk, 0, stream>>>(q2hT, k2hT, scores, nullptr,
                                               512, 4096, 4096, 4096, 4096, 4096, sc2);
    softmax_rows<<<dim3(4096), blk, 0, stream>>>(scores);
    gemm_nt<<<dim3(32, 4), blk, 0, stream>>>(v2hT, scores, s2T + (size_t)h * 512 * 4096,
                                             512, 4096, 4096, 4096, 4096, 4096, 1, 0);
  }

  // ---- gn2 + row L2 normalize, in place: s2T becomes h2n [2048,4096]
  graph_norm_rows<true><<<dim3(2048), blk, 0, stream>>>(s2T, s2T, gn2w, gn2b, gn2ms);

  // ---- out = relu(h2n . h2n^T)  [2048,2048]
  gemm_nt<<<dim3(16, 16), blk, 0, stream>>>(s2T, s2T, (float*)d_out,
                                            2048, 2048, 4096, 4096, 4096, 2048, 0, 1);
}

// Round 2
// 778.071 us; speedup vs baseline: 8.2736x; 8.2736x over previous
//
#include <hip/hip_runtime.h>
#include <math.h>

typedef unsigned int u32;
typedef unsigned short ushort_t;
typedef __attribute__((ext_vector_type(8))) short short8;
typedef __attribute__((ext_vector_type(4))) float f32x4;

__device__ __forceinline__ ushort_t f2bf(float x) {
  u32 u = __float_as_uint(x);
  u32 r = (u + 0x7fffu + ((u >> 16) & 1u)) >> 16;
  return (ushort_t)r;
}
__device__ __forceinline__ float bf2f(ushort_t s) {
  return __uint_as_float(((u32)s) << 16);
}

// ---------------- block reduction helpers (256 threads = 4 waves) ----------
__device__ __forceinline__ float block_sum256(float v, float* red) {
  #pragma unroll
  for (int o = 32; o > 0; o >>= 1) v += __shfl_down(v, o, 64);
  __syncthreads();
  if ((threadIdx.x & 63) == 0) red[threadIdx.x >> 6] = v;
  __syncthreads();
  return red[0] + red[1] + red[2] + red[3];
}
__device__ __forceinline__ float block_max256(float v, float* red) {
  #pragma unroll
  for (int o = 32; o > 0; o >>= 1) v = fmaxf(v, __shfl_down(v, o, 64));
  __syncthreads();
  if ((threadIdx.x & 63) == 0) red[threadIdx.x >> 6] = v;
  __syncthreads();
  return fmaxf(fmaxf(red[0], red[1]), fmaxf(red[2], red[3]));
}

// ---------------- MFMA GEMM:  C[m,n] (op)= scale * sum_k A[m,k]*B[n,k] -----
// A:[M,K] bf16 row-major (lda), B:[N,K] bf16 row-major (ldb).
// M%128==0 grid.y tiles (stores guarded by Mvalid), N%128==0 grid.x tiles,
// K/Ksplit % 32 == 0. grid.z = Ksplit (CMODE must be 2 when Ksplit>1).
// CMODE: 0 = store f32 (+optional RELU), 1 = store bf16, 2 = atomicAdd f32.
template<int CMODE, bool RELU>
__global__ __launch_bounds__(256) void mfma_bt(
    const ushort_t* __restrict__ A, const ushort_t* __restrict__ B,
    void* __restrict__ Cv, int lda, int ldb, int ldc,
    int K, int Ksplit, int Mvalid, float scale)
{
  __shared__ ushort_t lsA[2][128 * 32];
  __shared__ ushort_t lsB[2][128 * 32];
  const int t  = threadIdx.x;
  const int m0 = blockIdx.y * 128;
  const int n0 = blockIdx.x * 128;
  const int Kc = K / Ksplit;
  const int NT = Kc / 32;
  const ushort_t* Ab = A + (size_t)m0 * lda + (size_t)blockIdx.z * Kc;
  const ushort_t* Bb = B + (size_t)n0 * ldb + (size_t)blockIdx.z * Kc;

  const int cs = t & 3;

  f32x4 acc[4][4];
  #pragma unroll
  for (int i = 0; i < 4; ++i)
    #pragma unroll
    for (int j = 0; j < 4; ++j) acc[i][j] = (f32x4){0.f, 0.f, 0.f, 0.f};

  const int lane = t & 63;
  const int wv = t >> 6;
  const int wr = (wv >> 1) * 64;   // wave M offset in tile
  const int wc = (wv & 1) * 64;    // wave N offset in tile
  const int lr = lane & 15;
  const int kc = lane >> 4;        // k-chunk 0..3

  // ds_read byte offsets within one 8 KB half (swizzled chunk layout)
  int roffA[4], roffB[4];
  #pragma unroll
  for (int m = 0; m < 4; ++m) {
    int ra = wr + m * 16 + lr;
    roffA[m] = ra * 64 + ((kc ^ (ra & 3)) * 16);
    int rb = wc + m * 16 + lr;
    roffB[m] = rb * 64 + ((kc ^ (rb & 3)) * 16);
  }

  auto stage = [&](int buf, int kt) {
    const ushort_t* As = Ab + kt * 32;
    const ushort_t* Bs = Bb + kt * 32;
    #pragma unroll
    for (int i = 0; i < 2; ++i) {
      int s = t + i * 256;
      int r = s >> 2;
      int c = cs ^ (r & 3);     // inverse-swizzled global source, linear LDS dest
      __builtin_amdgcn_global_load_lds(
          (const __attribute__((address_space(1))) u32*)(As + (size_t)r * lda + c * 8),
          (__attribute__((address_space(3))) u32*)(&lsA[buf][s * 8]), 16, 0, 0);
    }
    #pragma unroll
    for (int i = 0; i < 2; ++i) {
      int s = t + i * 256;
      int r = s >> 2;
      int c = cs ^ (r & 3);
      __builtin_amdgcn_global_load_lds(
          (const __attribute__((address_space(1))) u32*)(Bs + (size_t)r * ldb + c * 8),
          (__attribute__((address_space(3))) u32*)(&lsB[buf][s * 8]), 16, 0, 0);
    }
  };

  stage(0, 0);
  __syncthreads();
  int cur = 0;
  for (int kt = 0; kt < NT; ++kt) {
    if (kt + 1 < NT) stage(cur ^ 1, kt + 1);
    short8 af[4], bfr[4];
    const char* baseA = (const char*)&lsA[cur][0];
    const char* baseB = (const char*)&lsB[cur][0];
    #pragma unroll
    for (int m = 0; m < 4; ++m) af[m]  = *(const short8*)(baseA + roffA[m]);
    #pragma unroll
    for (int n = 0; n < 4; ++n) bfr[n] = *(const short8*)(baseB + roffB[n]);
    #pragma unroll
    for (int m = 0; m < 4; ++m)
      #pragma unroll
      for (int n = 0; n < 4; ++n)
        acc[m][n] = __builtin_amdgcn_mfma_f32_16x16x32_bf16(af[m], bfr[n], acc[m][n], 0, 0, 0);
    __syncthreads();
    cur ^= 1;
  }

  const int row4 = (lane >> 4) * 4;
  const int coln = lane & 15;
  #pragma unroll
  for (int m = 0; m < 4; ++m) {
    #pragma unroll
    for (int r = 0; r < 4; ++r) {
      const int gm = m0 + wr + m * 16 + row4 + r;
      if (gm < Mvalid) {
        #pragma unroll
        for (int n = 0; n < 4; ++n) {
          const int gn = n0 + wc + n * 16 + coln;
          float v = acc[m][n][r] * scale;
          if (RELU) v = fmaxf(v, 0.f);
          if (CMODE == 0)      ((float*)Cv)[(size_t)gm * ldc + gn] = v;
          else if (CMODE == 1) ((ushort_t*)Cv)[(size_t)gm * ldc + gn] = f2bf(v);
          else                 atomicAdd(&((float*)Cv)[(size_t)gm * ldc + gn], v);
        }
      }
    }
  }
}

// ---------------- weights: dst[Mp,Kp] bf16 = W^T (+ bias slot at k==Kv) ----
// dst row m -> h = m/PADH, c = m%PADH, src fout = h*VALH+c (valid if c<VALH).
__global__ __launch_bounds__(256) void wt_conv(
    const float* __restrict__ W, const float* __restrict__ bias,
    ushort_t* __restrict__ dst, int Mtot, int ldw, int Kv, int Kp,
    int PADH, int VALH)
{
  const int m = blockIdx.x;
  const int h = m / PADH, c0 = m % PADH;
  const int fout = h * VALH + c0;
  const bool valid = (c0 < VALH) && (fout < Mtot);
  for (int k = threadIdx.x; k < Kp; k += blockDim.x) {
    float v = 0.f;
    if (valid) {
      if (k < Kv) v = W[(size_t)k * ldw + fout];
      else if (k == Kv) v = bias[fout];
    }
    dst[(size_t)m * Kp + k] = f2bf(v);
  }
}

// ---------------- transpose fp32 [Kv,4096] -> bf16 [4096,Kp], bias slot ----
__global__ __launch_bounds__(256) void trans_pad(
    const float* __restrict__ src, ushort_t* __restrict__ dst, int Kv, int Kp)
{
  __shared__ float tl[64][65];
  const int t = threadIdx.x;
  const int f0 = blockIdx.x * 64;
  const int i0 = blockIdx.y * 64;
  const int c = t & 63, rbase = t >> 6;
  #pragma unroll
  for (int it = 0; it < 16; ++it) {
    int r = rbase + it * 4;
    int f = f0 + r;
    tl[r][c] = (f < Kv) ? src[(size_t)f * 4096 + i0 + c] : 0.f;
  }
  __syncthreads();
  #pragma unroll
  for (int it = 0; it < 16; ++it) {
    int r = rbase + it * 4;
    int f = f0 + c;
    if (f < Kp) {
      float v = (f < Kv) ? tl[c][r] : ((f == Kv) ? 1.f : 0.f);
      dst[(size_t)(i0 + r) * Kp + f] = f2bf(v);
    }
  }
}

// ---------------- row softmax, bf16 in/out, in place, 4096 cols ------------
__global__ __launch_bounds__(256) void softmax_bf16(ushort_t* __restrict__ S)
{
  __shared__ float red[4];
  const int t = threadIdx.x;
  uint4* row = (uint4*)(S + (size_t)blockIdx.x * 4096);
  uint4 d0 = row[t], d1 = row[t + 256];
  float v[16];
  {
    const u32* u = (const u32*)&d0;
    #pragma unroll
    for (int q = 0; q < 4; ++q) {
      v[q * 2]     = __uint_as_float((u[q] & 0xffffu) << 16);
      v[q * 2 + 1] = __uint_as_float(u[q] & 0xffff0000u);
    }
    const u32* w = (const u32*)&d1;
    #pragma unroll
    for (int q = 0; q < 4; ++q) {
      v[8 + q * 2]     = __uint_as_float((w[q] & 0xffffu) << 16);
      v[8 + q * 2 + 1] = __uint_as_float(w[q] & 0xffff0000u);
    }
  }
  float mx = v[0];
  #pragma unroll
  for (int e = 1; e < 16; ++e) mx = fmaxf(mx, v[e]);
  mx = block_max256(mx, red);
  float sum = 0.f;
  #pragma unroll
  for (int e = 0; e < 16; ++e) { v[e] = __expf(v[e] - mx); sum += v[e]; }
  sum = block_sum256(sum, red);
  const float inv = 1.f / sum;
  u32 o0[4], o1[4];
  #pragma unroll
  for (int q = 0; q < 4; ++q) {
    o0[q] = (u32)f2bf(v[q * 2] * inv) | ((u32)f2bf(v[q * 2 + 1] * inv) << 16);
    o1[q] = (u32)f2bf(v[8 + q * 2] * inv) | ((u32)f2bf(v[8 + q * 2 + 1] * inv) << 16);
  }
  row[t]       = *(uint4*)o0;
  row[t + 256] = *(uint4*)o1;
}

// ---------------- GraphNorm per feature row over 4096 nodes ----------------
template<bool L2NORM, bool BF16OUT>
__global__ __launch_bounds__(256) void graph_norm_rows(
    const float* __restrict__ X, void* __restrict__ Yv,
    const float* __restrict__ w, const float* __restrict__ b,
    const float* __restrict__ ms)
{
  __shared__ float red[4];
  const int t = threadIdx.x;
  const int row = blockIdx.x;
  const float* x = X + (size_t)row * 4096;
  float v[16];
  float s = 0.f;
  #pragma unroll
  for (int e = 0; e < 4; ++e) {
    *(float4*)&v[e * 4] = *(const float4*)&x[t * 4 + 1024 * e];
    #pragma unroll
    for (int q = 0; q < 4; ++q) s += v[e * 4 + q];
  }
  const float mean = block_sum256(s, red) * (1.f / 4096.f);
  const float sub = mean * ms[row];
  float s2 = 0.f;
  #pragma unroll
  for (int e = 0; e < 16; ++e) { v[e] -= sub; s2 += v[e] * v[e]; }
  const float var = block_sum256(s2, red) * (1.f / 4096.f);
  const float scl = rsqrtf(var + 1e-5f) * w[row];
  const float bb = b[row];
  #pragma unroll
  for (int e = 0; e < 16; ++e) v[e] = v[e] * scl + bb;
  float osc = 1.f;
  if (L2NORM) {
    float s3 = 0.f;
    #pragma unroll
    for (int e = 0; e < 16; ++e) s3 += v[e] * v[e];
    osc = rsqrtf(block_sum256(s3, red));
  }
  if (BF16OUT) {
    ushort_t* y = (ushort_t*)Yv + (size_t)row * 4096;
    #pragma unroll
    for (int e = 0; e < 4; ++e) {
      ushort_t o0[4];
      #pragma unroll
      for (int q = 0; q < 4; ++q) o0[q] = f2bf(v[e * 4 + q] * osc);
      *(ushort2*)&y[t * 4 + 1024 * e] = *(ushort2*)&o0[0];
      *(ushort2*)&y[t * 4 + 1024 * e + 2] = *(ushort2*)&o0[2];
    }
  } else {
    float* y = (float*)Yv + (size_t)row * 4096;
    #pragma unroll
    for (int e = 0; e < 4; ++e) {
      float o0[4];
      #pragma unroll
      for (int q = 0; q < 4; ++q) o0[q] = v[e * 4 + q] * osc;
      *(float4*)&y[t * 4 + 1024 * e] = *(float4*)&o0[0];
    }
  }
}

extern "C" void kernel_launch(void* const* d_in, const int* in_sizes, int n_in,
                              void* d_out, int out_size, void* d_ws, size_t ws_size,
                              hipStream_t stream)
{
  (void)in_sizes; (void)n_in; (void)out_size; (void)ws_size;
  const float* lr_x = (const float*)d_in[0];
  const float* Wq1 = (const float*)d_in[1];  const float* bq1 = (const float*)d_in[2];
  const float* Wk1 = (const float*)d_in[3];  const float* bk1 = (const float*)d_in[4];
  const float* Wv1 = (const float*)d_in[5];  const float* bv1 = (const float*)d_in[6];
  const float* Ws1 = (const float*)d_in[7];  const float* bs1 = (const float*)d_in[8];
  const float* gn1w = (const float*)d_in[9]; const float* gn1b = (const float*)d_in[10];
  const float* gn1ms = (const float*)d_in[11];
  const float* Wq2 = (const float*)d_in[12]; const float* bq2 = (const float*)d_in[13];
  const float* Wk2 = (const float*)d_in[14]; const float* bk2 = (const float*)d_in[15];
  const float* Wv2 = (const float*)d_in[16]; const float* bv2 = (const float*)d_in[17];
  const float* Ws2 = (const float*)d_in[18]; const float* bs2 = (const float*)d_in[19];
  const float* gn2w = (const float*)d_in[20]; const float* gn2b = (const float*)d_in[21];
  const float* gn2ms = (const float*)d_in[22];

  char* p = (char*)d_ws;
  auto alloc = [&](size_t bytes) { char* r = p; p += (bytes + 255) & ~(size_t)255; return r; };
  ushort_t* Pb   = (ushort_t*)alloc((size_t)4096 * 4096 * 2);  // scores/P bf16, in place
  ushort_t* xb   = (ushort_t*)alloc((size_t)4096 * 544 * 2);   // lr_x^T + bias slot
  ushort_t* qk1b = (ushort_t*)alloc((size_t)4096 * 512 * 2);   // [4096, 4h*64(q) | 4h*64(k)]
  ushort_t* v1b  = (ushort_t*)alloc((size_t)512 * 4096 * 2);   // [4h*128, 4096]
  float*    s1T  = (float*)   alloc((size_t)200 * 4096 * 4);
  float*    h1nT = (float*)   alloc((size_t)200 * 4096 * 4);
  ushort_t* h1nb = (ushort_t*)alloc((size_t)4096 * 224 * 2);   // h1n^T + bias slot
  ushort_t* Wqk1 = (ushort_t*)alloc((size_t)512 * 544 * 2);
  ushort_t* Wv1b = (ushort_t*)alloc((size_t)512 * 544 * 2);
  ushort_t* Ws1b = (ushort_t*)alloc((size_t)256 * 544 * 2);
  ushort_t* Wqk2 = (ushort_t*)alloc((size_t)4096 * 224 * 2);
  ushort_t* Wv2b = (ushort_t*)alloc((size_t)2048 * 224 * 2);
  ushort_t* Ws2b = (ushort_t*)alloc((size_t)2048 * 224 * 2);
  ushort_t* qk2b = (ushort_t*)alloc((size_t)4096 * 4096 * 2);  // [4096, 2048(q)|2048(k)]
  ushort_t* v2T  = (ushort_t*)alloc((size_t)2048 * 4096 * 2);
  float*    s2T  = (float*)   alloc((size_t)2048 * 4096 * 4);
  ushort_t* h2b  = (ushort_t*)alloc((size_t)2048 * 4096 * 2);

  const dim3 blk(256, 1, 1);
  const float sc1 = 0.14142135623730951f;  // 1/sqrt(50)
  const float sc2 = 0.04419417382415922f;  // 1/sqrt(512)

  // ---- weight conversions (bf16, transposed, K-padded, bias folded at k==Kv)
  wt_conv<<<dim3(256),  blk, 0, stream>>>(Wq1, bq1, Wqk1,             200, 200, 512, 544, 64, 50);
  wt_conv<<<dim3(256),  blk, 0, stream>>>(Wk1, bk1, Wqk1 + 256 * 544, 200, 200, 512, 544, 64, 50);
  wt_conv<<<dim3(512),  blk, 0, stream>>>(Wv1, bv1, Wv1b,             200, 200, 512, 544, 128, 50);
  wt_conv<<<dim3(256),  blk, 0, stream>>>(Ws1, bs1, Ws1b,             200, 200, 512, 544, 256, 200);
  wt_conv<<<dim3(2048), blk, 0, stream>>>(Wq2, bq2, Wqk2,              2048, 2048, 200, 224, 2048, 2048);
  wt_conv<<<dim3(2048), blk, 0, stream>>>(Wk2, bk2, Wqk2 + 2048 * 224, 2048, 2048, 200, 224, 2048, 2048);
  wt_conv<<<dim3(2048), blk, 0, stream>>>(Wv2, bv2, Wv2b,              2048, 2048, 200, 224, 2048, 2048);
  wt_conv<<<dim3(2048), blk, 0, stream>>>(Ws2, bs2, Ws2b,              2048, 2048, 200, 224, 2048, 2048);
  // ---- x^T -> bf16 [4096, 544], col 512 = 1.0 (bias slot)
  trans_pad<<<dim3(9, 64), blk, 0, stream>>>(lr_x, xb, 512, 544);

  // ---- layer-1 projections (MFMA)
  mfma_bt<1, false><<<dim3(4, 32), blk, 0, stream>>>(xb, Wqk1, qk1b, 544, 544, 512, 544, 1, 4096, 1.f);
  mfma_bt<1, false><<<dim3(32, 4), blk, 0, stream>>>(Wv1b, xb, v1b, 544, 544, 4096, 544, 1, 512, 1.f);
  mfma_bt<0, false><<<dim3(32, 2), blk, 0, stream>>>(Ws1b, xb, s1T, 544, 544, 4096, 544, 1, 200, 1.f);

  // ---- attention 1 (C=50, K padded to 64) per head
  for (int h = 0; h < 4; ++h) {
    mfma_bt<1, false><<<dim3(32, 32), blk, 0, stream>>>(
        qk1b + h * 64, qk1b + 256 + h * 64, Pb, 512, 512, 4096, 64, 1, 4096, sc1);
    softmax_bf16<<<dim3(4096), blk, 0, stream>>>(Pb);
    mfma_bt<2, false><<<dim3(32, 1, 8), blk, 0, stream>>>(
        v1b + (size_t)h * 128 * 4096, Pb, s1T + (size_t)h * 50 * 4096,
        4096, 4096, 4096, 4096, 8, 50, 1.f);
  }
  graph_norm_rows<false, false><<<dim3(200), blk, 0, stream>>>(s1T, h1nT, gn1w, gn1b, gn1ms);
  trans_pad<<<dim3(4, 64), blk, 0, stream>>>(h1nT, h1nb, 200, 224);

  // ---- layer-2 projections (MFMA)
  mfma_bt<1, false><<<dim3(32, 32), blk, 0, stream>>>(h1nb, Wqk2, qk2b, 224, 224, 4096, 224, 1, 4096, 1.f);
  mfma_bt<1, false><<<dim3(32, 16), blk, 0, stream>>>(Wv2b, h1nb, v2T, 224, 224, 4096, 224, 1, 2048, 1.f);
  mfma_bt<0, false><<<dim3(32, 16), blk, 0, stream>>>(Ws2b, h1nb, s2T, 224, 224, 4096, 224, 1, 2048, 1.f);

  // ---- attention 2 (C=512) per head
  for (int h = 0; h < 4; ++h) {
    mfma_bt<1, false><<<dim3(32, 32), blk, 0, stream>>>(
        qk2b + h * 512, qk2b + 2048 + h * 512, Pb, 4096, 4096, 4096, 512, 1, 4096, sc2);
    softmax_bf16<<<dim3(4096), blk, 0, stream>>>(Pb);
    mfma_bt<2, false><<<dim3(32, 4, 2), blk, 0, stream>>>(
        v2T + (size_t)h * 512 * 4096, Pb, s2T + (size_t)h * 512 * 4096,
        4096, 4096, 4096, 4096, 2, 512, 1.f);
  }

  // ---- gn2 + row L2 normalize -> h2b (bf16)
  graph_norm_rows<true, true><<<dim3(2048), blk, 0, stream>>>(s2T, h2b, gn2w, gn2b, gn2ms);

  // ---- out = relu(h2n . h2n^T)  [2048, 2048] fp32
  mfma_bt<0, true><<<dim3(16, 16), blk, 0, stream>>>(h2b, h2b, (float*)d_out,
                                                     4096, 4096, 2048, 4096, 1, 2048, 1.f);
}

// Round 3
// 699.861 us; speedup vs baseline: 9.1981x; 1.1118x over previous
//
#include <hip/hip_runtime.h>
#include <math.h>

typedef unsigned int u32;
typedef unsigned short ushort_t;
typedef __attribute__((ext_vector_type(8))) short short8;
typedef __attribute__((ext_vector_type(4))) float f32x4;

__device__ __forceinline__ ushort_t f2bf(float x) {
  u32 u = __float_as_uint(x);
  u32 r = (u + 0x7fffu + ((u >> 16) & 1u)) >> 16;
  return (ushort_t)r;
}

// ---------------- block reduction helpers (256 threads = 4 waves) ----------
__device__ __forceinline__ float block_sum256(float v, float* red) {
  #pragma unroll
  for (int o = 32; o > 0; o >>= 1) v += __shfl_down(v, o, 64);
  __syncthreads();
  if ((threadIdx.x & 63) == 0) red[threadIdx.x >> 6] = v;
  __syncthreads();
  return red[0] + red[1] + red[2] + red[3];
}
__device__ __forceinline__ float block_max256(float v, float* red) {
  #pragma unroll
  for (int o = 32; o > 0; o >>= 1) v = fmaxf(v, __shfl_down(v, o, 64));
  __syncthreads();
  if ((threadIdx.x & 63) == 0) red[threadIdx.x >> 6] = v;
  __syncthreads();
  return fmaxf(fmaxf(red[0], red[1]), fmaxf(red[2], red[3]));
}

// ================= 256x256-tile MFMA GEMM, 512 threads, 2-phase ============
// C[m,n] (op)= scale * sum_k A[m,k]*B[n,k];  A:[M,K] bf16, B:[N,K] bf16.
// M,N multiples of 256 (tiles), K/zsplit % 32 == 0.
// zsplit>1: grid.z = K-split (CMODE must be 2).  zsplit==1: grid.z = batch,
//   A+=z*zA, B+=z*zB, C+=z*zC.
// bShift>=0: B += (m0>>bShift)*bHeadStride (per-m-tile head select).
// CMODE: 0 = store f32 (+RELU), 1 = store bf16, 2 = atomicAdd f32.
template<int CMODE, bool RELU>
__global__ __launch_bounds__(512) void mfma256(
    const ushort_t* __restrict__ A, const ushort_t* __restrict__ B,
    void* __restrict__ Cv, int lda, int ldb, int ldc,
    int K, int zsplit, size_t zA, size_t zB, size_t zC,
    int bShift, size_t bHeadStride, int Mvalid, float scale)
{
  __shared__ ushort_t lsA[2][256 * 32];   // 32 KB
  __shared__ ushort_t lsB[2][256 * 32];   // 32 KB  (total 64 KB)
  const int t = threadIdx.x;
  // bijective XCD-aware block swizzle (m204)
  const int gx = gridDim.x;
  const int nwg = gx * gridDim.y;
  const int bid = blockIdx.y * gx + blockIdx.x;
  const int qq = nwg >> 3, rr_ = nwg & 7;
  const int xcd = bid & 7, idx = bid >> 3;
  const int swz = (xcd < rr_ ? xcd * (qq + 1) : rr_ * (qq + 1) + (xcd - rr_) * qq) + idx;
  const int m0 = (swz / gx) * 256;
  const int n0 = (swz % gx) * 256;
  const int z = blockIdx.z;
  int Kc = K, kOff = 0;
  size_t aZ = 0, bZ = 0, cZ = 0;
  if (zsplit > 1) { Kc = K / zsplit; kOff = z * Kc; }
  else { aZ = (size_t)z * zA; bZ = (size_t)z * zB; cZ = (size_t)z * zC; }
  const ushort_t* Ab = A + aZ + (size_t)m0 * lda + kOff;
  const ushort_t* Bb = B + bZ + (size_t)n0 * ldb + kOff
                     + (bShift >= 0 ? (size_t)(m0 >> bShift) * bHeadStride : 0);
  const int NT = Kc / 32;

  f32x4 acc[8][4];
  #pragma unroll
  for (int i = 0; i < 8; ++i)
    #pragma unroll
    for (int j = 0; j < 4; ++j) acc[i][j] = (f32x4){0.f, 0.f, 0.f, 0.f};

  const int lane = t & 63;
  const int wv = t >> 6;
  const int wr = (wv >> 2) * 128;   // wave M offset (2 rows of waves)
  const int wc = (wv & 3) * 64;     // wave N offset (4 cols of waves)
  const int lr = lane & 15;
  const int kc = lane >> 4;         // 16B chunk within K=32 row

  // swizzled ds_read byte offsets (row stride 64B, 4 chunks, XOR row&3)
  int roffA[8], roffB[4];
  #pragma unroll
  for (int m = 0; m < 8; ++m) {
    int row = wr + m * 16 + lr;
    roffA[m] = row * 64 + ((kc ^ (row & 3)) * 16);
  }
  #pragma unroll
  for (int n = 0; n < 4; ++n) {
    int row = wc + n * 16 + lr;
    roffB[n] = row * 64 + ((kc ^ (row & 3)) * 16);
  }

  auto stage = [&](int buf, int kt) {
    const ushort_t* As = Ab + kt * 32;
    const ushort_t* Bs = Bb + kt * 32;
    #pragma unroll
    for (int i = 0; i < 2; ++i) {
      int s = t + i * 512;
      int r = s >> 2;
      int c = (s & 3) ^ (r & 3);   // inverse-swizzled global source, linear LDS dest
      __builtin_amdgcn_global_load_lds(
          (const __attribute__((address_space(1))) u32*)(As + (size_t)r * lda + c * 8),
          (__attribute__((address_space(3))) u32*)(&lsA[buf][s * 8]), 16, 0, 0);
    }
    #pragma unroll
    for (int i = 0; i < 2; ++i) {
      int s = t + i * 512;
      int r = s >> 2;
      int c = (s & 3) ^ (r & 3);
      __builtin_amdgcn_global_load_lds(
          (const __attribute__((address_space(1))) u32*)(Bs + (size_t)r * ldb + c * 8),
          (__attribute__((address_space(3))) u32*)(&lsB[buf][s * 8]), 16, 0, 0);
    }
  };

  stage(0, 0);
  __syncthreads();
  int cur = 0;
  for (int kt = 0; kt < NT; ++kt) {
    if (kt + 1 < NT) stage(cur ^ 1, kt + 1);
    const char* baseA = (const char*)&lsA[cur][0];
    const char* baseB = (const char*)&lsB[cur][0];
    short8 af[8], bf_[4];
    #pragma unroll
    for (int m = 0; m < 8; ++m) af[m] = *(const short8*)(baseA + roffA[m]);
    #pragma unroll
    for (int n = 0; n < 4; ++n) bf_[n] = *(const short8*)(baseB + roffB[n]);
    #pragma unroll
    for (int m = 0; m < 8; ++m)
      #pragma unroll
      for (int n = 0; n < 4; ++n)
        acc[m][n] = __builtin_amdgcn_mfma_f32_16x16x32_bf16(af[m], bf_[n], acc[m][n], 0, 0, 0);
    __syncthreads();
    cur ^= 1;
  }

  const int row4 = (lane >> 4) * 4;
  const int coln = lane & 15;
  #pragma unroll
  for (int m = 0; m < 8; ++m) {
    #pragma unroll
    for (int r = 0; r < 4; ++r) {
      const int gm = m0 + wr + m * 16 + row4 + r;
      if (gm < Mvalid) {
        #pragma unroll
        for (int n = 0; n < 4; ++n) {
          const int gn = n0 + wc + n * 16 + coln;
          float v = acc[m][n][r] * scale;
          if (RELU) v = fmaxf(v, 0.f);
          if (CMODE == 0)      ((float*)(((char*)Cv)) + cZ)[(size_t)gm * ldc + gn] = v;
          else if (CMODE == 1) ((ushort_t*)Cv + cZ)[(size_t)gm * ldc + gn] = f2bf(v);
          else                 atomicAdd(&((float*)Cv + cZ)[(size_t)gm * ldc + gn], v);
        }
      }
    }
  }
}

// ================= 128x128-tile MFMA GEMM (R2-proven), 256 threads =========
template<int CMODE, bool RELU>
__global__ __launch_bounds__(256) void mfma_bt(
    const ushort_t* __restrict__ A, const ushort_t* __restrict__ B,
    void* __restrict__ Cv, int lda, int ldb, int ldc,
    int K, int Ksplit, int Mvalid, float scale)
{
  __shared__ ushort_t lsA[2][128 * 32];
  __shared__ ushort_t lsB[2][128 * 32];
  const int t  = threadIdx.x;
  const int m0 = blockIdx.y * 128;
  const int n0 = blockIdx.x * 128;
  const int Kc = K / Ksplit;
  const int NT = Kc / 32;
  const ushort_t* Ab = A + (size_t)m0 * lda + (size_t)blockIdx.z * Kc;
  const ushort_t* Bb = B + (size_t)n0 * ldb + (size_t)blockIdx.z * Kc;
  const int cs = t & 3;

  f32x4 acc[4][4];
  #pragma unroll
  for (int i = 0; i < 4; ++i)
    #pragma unroll
    for (int j = 0; j < 4; ++j) acc[i][j] = (f32x4){0.f, 0.f, 0.f, 0.f};

  const int lane = t & 63;
  const int wv = t >> 6;
  const int wr = (wv >> 1) * 64;
  const int wc = (wv & 1) * 64;
  const int lr = lane & 15;
  const int kc = lane >> 4;

  int roffA[4], roffB[4];
  #pragma unroll
  for (int m = 0; m < 4; ++m) {
    int ra = wr + m * 16 + lr;
    roffA[m] = ra * 64 + ((kc ^ (ra & 3)) * 16);
    int rb = wc + m * 16 + lr;
    roffB[m] = rb * 64 + ((kc ^ (rb & 3)) * 16);
  }

  auto stage = [&](int buf, int kt) {
    const ushort_t* As = Ab + kt * 32;
    const ushort_t* Bs = Bb + kt * 32;
    #pragma unroll
    for (int i = 0; i < 2; ++i) {
      int s = t + i * 256;
      int r = s >> 2;
      int c = cs ^ (r & 3);
      __builtin_amdgcn_global_load_lds(
          (const __attribute__((address_space(1))) u32*)(As + (size_t)r * lda + c * 8),
          (__attribute__((address_space(3))) u32*)(&lsA[buf][s * 8]), 16, 0, 0);
    }
    #pragma unroll
    for (int i = 0; i < 2; ++i) {
      int s = t + i * 256;
      int r = s >> 2;
      int c = cs ^ (r & 3);
      __builtin_amdgcn_global_load_lds(
          (const __attribute__((address_space(1))) u32*)(Bs + (size_t)r * ldb + c * 8),
          (__attribute__((address_space(3))) u32*)(&lsB[buf][s * 8]), 16, 0, 0);
    }
  };

  stage(0, 0);
  __syncthreads();
  int cur = 0;
  for (int kt = 0; kt < NT; ++kt) {
    if (kt + 1 < NT) stage(cur ^ 1, kt + 1);
    short8 af[4], bfr[4];
    const char* baseA = (const char*)&lsA[cur][0];
    const char* baseB = (const char*)&lsB[cur][0];
    #pragma unroll
    for (int m = 0; m < 4; ++m) af[m]  = *(const short8*)(baseA + roffA[m]);
    #pragma unroll
    for (int n = 0; n < 4; ++n) bfr[n] = *(const short8*)(baseB + roffB[n]);
    #pragma unroll
    for (int m = 0; m < 4; ++m)
      #pragma unroll
      for (int n = 0; n < 4; ++n)
        acc[m][n] = __builtin_amdgcn_mfma_f32_16x16x32_bf16(af[m], bfr[n], acc[m][n], 0, 0, 0);
    __syncthreads();
    cur ^= 1;
  }

  const int row4 = (lane >> 4) * 4;
  const int coln = lane & 15;
  #pragma unroll
  for (int m = 0; m < 4; ++m) {
    #pragma unroll
    for (int r = 0; r < 4; ++r) {
      const int gm = m0 + wr + m * 16 + row4 + r;
      if (gm < Mvalid) {
        #pragma unroll
        for (int n = 0; n < 4; ++n) {
          const int gn = n0 + wc + n * 16 + coln;
          float v = acc[m][n][r] * scale;
          if (RELU) v = fmaxf(v, 0.f);
          if (CMODE == 0)      ((float*)Cv)[(size_t)gm * ldc + gn] = v;
          else if (CMODE == 1) ((ushort_t*)Cv)[(size_t)gm * ldc + gn] = f2bf(v);
          else                 atomicAdd(&((float*)Cv)[(size_t)gm * ldc + gn], v);
        }
      }
    }
  }
}

// ---------------- weights: dst[Mp,Kp] bf16 = W^T (+ bias slot at k==Kv) ----
__global__ __launch_bounds__(256) void wt_conv(
    const float* __restrict__ W, const float* __restrict__ bias,
    ushort_t* __restrict__ dst, int Mtot, int ldw, int Kv, int Kp,
    int PADH, int VALH)
{
  const int m = blockIdx.x;
  const int h = m / PADH, c0 = m % PADH;
  const int fout = h * VALH + c0;
  const bool valid = (c0 < VALH) && (fout < Mtot);
  for (int k = threadIdx.x; k < Kp; k += blockDim.x) {
    float v = 0.f;
    if (valid) {
      if (k < Kv) v = W[(size_t)k * ldw + fout];
      else if (k == Kv) v = bias[fout];
    }
    dst[(size_t)m * Kp + k] = f2bf(v);
  }
}

// ---------------- transpose fp32 [Kv,4096] -> bf16 [4096,Kp], bias slot ----
__global__ __launch_bounds__(256) void trans_pad(
    const float* __restrict__ src, ushort_t* __restrict__ dst, int Kv, int Kp)
{
  __shared__ float tl[64][65];
  const int t = threadIdx.x;
  const int f0 = blockIdx.x * 64;
  const int i0 = blockIdx.y * 64;
  const int c = t & 63, rbase = t >> 6;
  #pragma unroll
  for (int it = 0; it < 16; ++it) {
    int r = rbase + it * 4;
    int f = f0 + r;
    tl[r][c] = (f < Kv) ? src[(size_t)f * 4096 + i0 + c] : 0.f;
  }
  __syncthreads();
  #pragma unroll
  for (int it = 0; it < 16; ++it) {
    int r = rbase + it * 4;
    int f = f0 + c;
    if (f < Kp) {
      float v = (f < Kv) ? tl[c][r] : ((f == Kv) ? 1.f : 0.f);
      dst[(size_t)(i0 + r) * Kp + f] = f2bf(v);
    }
  }
}

// ---------------- row softmax, bf16 in/out, in place, 4096 cols ------------
__global__ __launch_bounds__(256) void softmax_bf16(ushort_t* __restrict__ S)
{
  __shared__ float red[4];
  const int t = threadIdx.x;
  uint4* row = (uint4*)(S + (size_t)blockIdx.x * 4096);
  uint4 d0 = row[t], d1 = row[t + 256];
  float v[16];
  {
    const u32* u = (const u32*)&d0;
    #pragma unroll
    for (int q = 0; q < 4; ++q) {
      v[q * 2]     = __uint_as_float((u[q] & 0xffffu) << 16);
      v[q * 2 + 1] = __uint_as_float(u[q] & 0xffff0000u);
    }
    const u32* w = (const u32*)&d1;
    #pragma unroll
    for (int q = 0; q < 4; ++q) {
      v[8 + q * 2]     = __uint_as_float((w[q] & 0xffffu) << 16);
      v[8 + q * 2 + 1] = __uint_as_float(w[q] & 0xffff0000u);
    }
  }
  float mx = v[0];
  #pragma unroll
  for (int e = 1; e < 16; ++e) mx = fmaxf(mx, v[e]);
  mx = block_max256(mx, red);
  float sum = 0.f;
  #pragma unroll
  for (int e = 0; e < 16; ++e) { v[e] = __expf(v[e] - mx); sum += v[e]; }
  sum = block_sum256(sum, red);
  const float inv = 1.f / sum;
  u32 o0[4], o1[4];
  #pragma unroll
  for (int q = 0; q < 4; ++q) {
    o0[q] = (u32)f2bf(v[q * 2] * inv) | ((u32)f2bf(v[q * 2 + 1] * inv) << 16);
    o1[q] = (u32)f2bf(v[8 + q * 2] * inv) | ((u32)f2bf(v[8 + q * 2 + 1] * inv) << 16);
  }
  row[t]       = *(uint4*)o0;
  row[t + 256] = *(uint4*)o1;
}

// ---------------- GraphNorm per feature row over 4096 nodes ----------------
template<bool L2NORM, bool BF16OUT>
__global__ __launch_bounds__(256) void graph_norm_rows(
    const float* __restrict__ X, void* __restrict__ Yv,
    const float* __restrict__ w, const float* __restrict__ b,
    const float* __restrict__ ms)
{
  __shared__ float red[4];
  const int t = threadIdx.x;
  const int row = blockIdx.x;
  const float* x = X + (size_t)row * 4096;
  float v[16];
  float s = 0.f;
  #pragma unroll
  for (int e = 0; e < 4; ++e) {
    *(float4*)&v[e * 4] = *(const float4*)&x[t * 4 + 1024 * e];
    #pragma unroll
    for (int q = 0; q < 4; ++q) s += v[e * 4 + q];
  }
  const float mean = block_sum256(s, red) * (1.f / 4096.f);
  const float sub = mean * ms[row];
  float s2 = 0.f;
  #pragma unroll
  for (int e = 0; e < 16; ++e) { v[e] -= sub; s2 += v[e] * v[e]; }
  const float var = block_sum256(s2, red) * (1.f / 4096.f);
  const float scl = rsqrtf(var + 1e-5f) * w[row];
  const float bb = b[row];
  #pragma unroll
  for (int e = 0; e < 16; ++e) v[e] = v[e] * scl + bb;
  float osc = 1.f;
  if (L2NORM) {
    float s3 = 0.f;
    #pragma unroll
    for (int e = 0; e < 16; ++e) s3 += v[e] * v[e];
    osc = rsqrtf(block_sum256(s3, red));
  }
  if (BF16OUT) {
    ushort_t* y = (ushort_t*)Yv + (size_t)row * 4096;
    #pragma unroll
    for (int e = 0; e < 4; ++e) {
      ushort_t o0[4];
      #pragma unroll
      for (int q = 0; q < 4; ++q) o0[q] = f2bf(v[e * 4 + q] * osc);
      *(ushort2*)&y[t * 4 + 1024 * e] = *(ushort2*)&o0[0];
      *(ushort2*)&y[t * 4 + 1024 * e + 2] = *(ushort2*)&o0[2];
    }
  } else {
    float* y = (float*)Yv + (size_t)row * 4096;
    #pragma unroll
    for (int e = 0; e < 4; ++e) {
      float o0[4];
      #pragma unroll
      for (int q = 0; q < 4; ++q) o0[q] = v[e * 4 + q] * osc;
      *(float4*)&y[t * 4 + 1024 * e] = *(float4*)&o0[0];
    }
  }
}

// ---------------- in-place relu over float4s -------------------------------
__global__ __launch_bounds__(256) void relu_inplace(float* __restrict__ p)
{
  const size_t i = (size_t)blockIdx.x * 256 + threadIdx.x;
  float4 v = ((float4*)p)[i];
  v.x = fmaxf(v.x, 0.f); v.y = fmaxf(v.y, 0.f);
  v.z = fmaxf(v.z, 0.f); v.w = fmaxf(v.w, 0.f);
  ((float4*)p)[i] = v;
}

extern "C" void kernel_launch(void* const* d_in, const int* in_sizes, int n_in,
                              void* d_out, int out_size, void* d_ws, size_t ws_size,
                              hipStream_t stream)
{
  (void)in_sizes; (void)n_in; (void)out_size; (void)ws_size;
  const float* lr_x = (const float*)d_in[0];
  const float* Wq1 = (const float*)d_in[1];  const float* bq1 = (const float*)d_in[2];
  const float* Wk1 = (const float*)d_in[3];  const float* bk1 = (const float*)d_in[4];
  const float* Wv1 = (const float*)d_in[5];  const float* bv1 = (const float*)d_in[6];
  const float* Ws1 = (const float*)d_in[7];  const float* bs1 = (const float*)d_in[8];
  const float* gn1w = (const float*)d_in[9]; const float* gn1b = (const float*)d_in[10];
  const float* gn1ms = (const float*)d_in[11];
  const float* Wq2 = (const float*)d_in[12]; const float* bq2 = (const float*)d_in[13];
  const float* Wk2 = (const float*)d_in[14]; const float* bk2 = (const float*)d_in[15];
  const float* Wv2 = (const float*)d_in[16]; const float* bv2 = (const float*)d_in[17];
  const float* Ws2 = (const float*)d_in[18]; const float* bs2 = (const float*)d_in[19];
  const float* gn2w = (const float*)d_in[20]; const float* gn2b = (const float*)d_in[21];
  const float* gn2ms = (const float*)d_in[22];

  char* p = (char*)d_ws;
  auto alloc = [&](size_t bytes) { char* r = p; p += (bytes + 255) & ~(size_t)255; return r; };
  const size_t PSTR = (size_t)4096 * 4096;                      // elements per P matrix
  ushort_t* Pall = (ushort_t*)alloc(PSTR * 4 * 2);              // 4 x [4096,4096] bf16
  ushort_t* xb   = (ushort_t*)alloc((size_t)4096 * 544 * 2);
  ushort_t* qk1b = (ushort_t*)alloc((size_t)4096 * 512 * 2);    // [4096, 4h*64(q)|4h*64(k)]
  ushort_t* v1b  = (ushort_t*)alloc((size_t)512 * 4096 * 2);    // [4h*128, 4096]
  float*    s1T  = (float*)   alloc((size_t)200 * 4096 * 4);
  float*    h1nT = (float*)   alloc((size_t)200 * 4096 * 4);
  ushort_t* h1nb = (ushort_t*)alloc((size_t)4096 * 256 * 2);    // h1n^T + bias, Kp=256
  ushort_t* Wqk1 = (ushort_t*)alloc((size_t)512 * 544 * 2);
  ushort_t* Wv1b = (ushort_t*)alloc((size_t)512 * 544 * 2);
  ushort_t* Ws1b = (ushort_t*)alloc((size_t)256 * 544 * 2);
  ushort_t* Wqk2 = (ushort_t*)alloc((size_t)4096 * 256 * 2);
  ushort_t* Wv2b = (ushort_t*)alloc((size_t)2048 * 256 * 2);
  ushort_t* Ws2b = (ushort_t*)alloc((size_t)2048 * 256 * 2);
  ushort_t* qk2b = (ushort_t*)alloc((size_t)4096 * 4096 * 2);   // [4096, 2048(q)|2048(k)]
  ushort_t* v2T  = (ushort_t*)alloc((size_t)2048 * 4096 * 2);
  float*    s2T  = (float*)   alloc((size_t)2048 * 4096 * 4);
  ushort_t* h2b  = (ushort_t*)alloc((size_t)2048 * 4096 * 2);

  const dim3 b256(256, 1, 1);
  const dim3 b512(512, 1, 1);
  const float sc1 = 0.14142135623730951f;  // 1/sqrt(50)
  const float sc2 = 0.04419417382415922f;  // 1/sqrt(512)

  // ---- weight conversions (layer1 Kp=544, layer2 Kp=256, bias at k==Kv)
  wt_conv<<<dim3(256),  b256, 0, stream>>>(Wq1, bq1, Wqk1,             200, 200, 512, 544, 64, 50);
  wt_conv<<<dim3(256),  b256, 0, stream>>>(Wk1, bk1, Wqk1 + 256 * 544, 200, 200, 512, 544, 64, 50);
  wt_conv<<<dim3(512),  b256, 0, stream>>>(Wv1, bv1, Wv1b,             200, 200, 512, 544, 128, 50);
  wt_conv<<<dim3(256),  b256, 0, stream>>>(Ws1, bs1, Ws1b,             200, 200, 512, 544, 256, 200);
  wt_conv<<<dim3(2048), b256, 0, stream>>>(Wq2, bq2, Wqk2,              2048, 2048, 200, 256, 2048, 2048);
  wt_conv<<<dim3(2048), b256, 0, stream>>>(Wk2, bk2, Wqk2 + 2048 * 256, 2048, 2048, 200, 256, 2048, 2048);
  wt_conv<<<dim3(2048), b256, 0, stream>>>(Wv2, bv2, Wv2b,              2048, 2048, 200, 256, 2048, 2048);
  wt_conv<<<dim3(2048), b256, 0, stream>>>(Ws2, bs2, Ws2b,              2048, 2048, 200, 256, 2048, 2048);
  trans_pad<<<dim3(9, 64), b256, 0, stream>>>(lr_x, xb, 512, 544);

  // ---- layer-1 projections (128^2 kernel)
  mfma_bt<1, false><<<dim3(4, 32), b256, 0, stream>>>(xb, Wqk1, qk1b, 544, 544, 512, 544, 1, 4096, 1.f);
  mfma_bt<1, false><<<dim3(32, 4), b256, 0, stream>>>(Wv1b, xb, v1b, 544, 544, 4096, 544, 1, 512, 1.f);
  mfma_bt<0, false><<<dim3(32, 2), b256, 0, stream>>>(Ws1b, xb, s1T, 544, 544, 4096, 544, 1, 200, 1.f);

  // ---- attention 1 (C=50, Kpad=64): scores per head -> one softmax -> PV
  for (int h = 0; h < 4; ++h)
    mfma_bt<1, false><<<dim3(32, 32), b256, 0, stream>>>(
        qk1b + h * 64, qk1b + 256 + h * 64, Pall + (size_t)h * PSTR,
        512, 512, 4096, 64, 1, 4096, sc1);
  softmax_bf16<<<dim3(16384), b256, 0, stream>>>(Pall);
  for (int h = 0; h < 4; ++h)
    mfma_bt<2, false><<<dim3(32, 1, 8), b256, 0, stream>>>(
        v1b + (size_t)h * 128 * 4096, Pall + (size_t)h * PSTR,
        s1T + (size_t)h * 50 * 4096, 4096, 4096, 4096, 4096, 8, 50, 1.f);
  graph_norm_rows<false, false><<<dim3(200), b256, 0, stream>>>(s1T, h1nT, gn1w, gn1b, gn1ms);
  trans_pad<<<dim3(4, 64), b256, 0, stream>>>(h1nT, h1nb, 200, 256);

  // ---- layer-2 projections (256^2 kernel, K=256)
  mfma256<1, false><<<dim3(16, 16), b512, 0, stream>>>(
      h1nb, Wqk2, qk2b, 256, 256, 4096, 256, 1, 0, 0, 0, -1, 0, 4096, 1.f);
  mfma256<1, false><<<dim3(16, 8), b512, 0, stream>>>(
      Wv2b, h1nb, v2T, 256, 256, 4096, 256, 1, 0, 0, 0, -1, 0, 2048, 1.f);
  mfma256<0, false><<<dim3(16, 8), b512, 0, stream>>>(
      Ws2b, h1nb, s2T, 256, 256, 4096, 256, 1, 0, 0, 0, -1, 0, 2048, 1.f);

  // ---- attention 2: scores all heads (z-batch) -> one softmax -> PV (batched)
  mfma256<1, false><<<dim3(16, 16, 4), b512, 0, stream>>>(
      qk2b, qk2b + 2048, Pall, 4096, 4096, 4096, 512, 1,
      512, 512, PSTR, -1, 0, 4096, sc2);
  softmax_bf16<<<dim3(16384), b256, 0, stream>>>(Pall);
  mfma256<2, false><<<dim3(16, 8, 2), b512, 0, stream>>>(
      v2T, Pall, s2T, 4096, 4096, 4096, 4096, 2,
      0, 0, 0, 9, PSTR, 2048, 1.f);

  // ---- gn2 + row L2 normalize -> h2b (bf16)
  graph_norm_rows<true, true><<<dim3(2048), b256, 0, stream>>>(s2T, h2b, gn2w, gn2b, gn2ms);

  // ---- out = relu(h2n . h2n^T): split-K atomic into zeroed d_out, then relu
  hipMemsetAsync(d_out, 0, (size_t)2048 * 2048 * 4, stream);
  mfma256<2, false><<<dim3(8, 8, 4), b512, 0, stream>>>(
      h2b, h2b, d_out, 4096, 4096, 2048, 4096, 4,
      0, 0, 0, -1, 0, 2048, 1.f);
  relu_inplace<<<dim3(4096), b256, 0, stream>>>((float*)d_out);
}

// Round 4
// 649.761 us; speedup vs baseline: 9.9074x; 1.0771x over previous
//
#include <hip/hip_runtime.h>
#include <math.h>

typedef unsigned int u32;
typedef unsigned short ushort_t;
typedef __attribute__((ext_vector_type(8))) short short8;
typedef __attribute__((ext_vector_type(4))) float f32x4;

__device__ __forceinline__ ushort_t f2bf(float x) {
  u32 u = __float_as_uint(x);
  u32 r = (u + 0x7fffu + ((u >> 16) & 1u)) >> 16;
  return (ushort_t)r;
}

// ---------------- block reduction helpers (256 threads = 4 waves) ----------
__device__ __forceinline__ float block_sum256(float v, float* red) {
  #pragma unroll
  for (int o = 32; o > 0; o >>= 1) v += __shfl_down(v, o, 64);
  __syncthreads();
  if ((threadIdx.x & 63) == 0) red[threadIdx.x >> 6] = v;
  __syncthreads();
  return red[0] + red[1] + red[2] + red[3];
}
__device__ __forceinline__ float block_max256(float v, float* red) {
  #pragma unroll
  for (int o = 32; o > 0; o >>= 1) v = fmaxf(v, __shfl_down(v, o, 64));
  __syncthreads();
  if ((threadIdx.x & 63) == 0) red[threadIdx.x >> 6] = v;
  __syncthreads();
  return fmaxf(fmaxf(red[0], red[1]), fmaxf(red[2], red[3]));
}

// =====================================================================
// 256x256-tile, 8-phase, counted-vmcnt MFMA GEMM (m201-style schedule).
// C[m,n] (op)= scale * sum_k A[m,k]*B[n,k];  A:[M,K] bf16, B:[N,K] bf16.
// BK=64, K/zsplit % 128 == 0. 512 thr = 8 waves (2M x 4N), 128 KiB LDS.
// zsplit>1: grid.z = K-split (CMODE must be 2). zsplit==1: grid.z = batch.
// bShift>=0: B += (m0>>bShift)*bHead (per-m-tile head select).
// CMODE: 0 = store f32 (+RELU), 1 = store bf16, 2 = atomicAdd f32.
// =====================================================================

// LDS swizzle: elem (row,k) at byte row*128 + (((k>>3) ^ (row&7))*16) + (k&7)*2.
// ds_read addr helpers (row&7 == lane&7 for all frags since wr,wc,16*m are =0 mod 8):
#define RD_A(bb, mm, cc) (*(const short8*)(lsAc + (bb)*32768 + arow + (mm)*2048 + (cc)))
#define RD_B(bb, nn, cc) (*(const short8*)(lsBc + (bb)*32768 + brow + (nn)*2048 + (cc)))

#define MM8(nn, bv) { \
  acc[0][nn] = __builtin_amdgcn_mfma_f32_16x16x32_bf16(a0, bv, acc[0][nn], 0,0,0); \
  acc[1][nn] = __builtin_amdgcn_mfma_f32_16x16x32_bf16(a1, bv, acc[1][nn], 0,0,0); \
  acc[2][nn] = __builtin_amdgcn_mfma_f32_16x16x32_bf16(a2, bv, acc[2][nn], 0,0,0); \
  acc[3][nn] = __builtin_amdgcn_mfma_f32_16x16x32_bf16(a3, bv, acc[3][nn], 0,0,0); \
  acc[4][nn] = __builtin_amdgcn_mfma_f32_16x16x32_bf16(a4, bv, acc[4][nn], 0,0,0); \
  acc[5][nn] = __builtin_amdgcn_mfma_f32_16x16x32_bf16(a5, bv, acc[5][nn], 0,0,0); \
  acc[6][nn] = __builtin_amdgcn_mfma_f32_16x16x32_bf16(a6, bv, acc[6][nn], 0,0,0); \
  acc[7][nn] = __builtin_amdgcn_mfma_f32_16x16x32_bf16(a7, bv, acc[7][nn], 0,0,0); }

// stage one 128-row half (2 x global_load_lds w=16) of a K-tile tt.
// Linear LDS dest; inverse-swizzled global source (both-sides rule).
#define STG(BASE, LD, LS, bb, hf, tt) { \
  _Pragma("unroll") \
  for (int ii = 0; ii < 2; ++ii) { \
    const int s_ = t + ii * 512; \
    const int r_ = s_ >> 3; \
    const int lc_ = (s_ & 7) ^ (r_ & 7); \
    __builtin_amdgcn_global_load_lds( \
      (const __attribute__((address_space(1))) u32*)((BASE) + (size_t)((hf) * 128 + r_) * (LD) + (size_t)(tt) * 64 + lc_ * 8), \
      (__attribute__((address_space(3))) u32*)(&(LS)[bb][(hf) * 8192 + s_ * 8]), 16, 0, 0); \
  } }

#define BAR() __builtin_amdgcn_s_barrier()
#define PRIO(x) __builtin_amdgcn_s_setprio(x)

// 4-phase group: computes K-tile in buf `bf` (k0/n01, k0/n23, k1/n01, k1/n23).
// Stages: p1 -> A-hi+B-lo(tS1) into buf^1; p2 -> B-hi(tS1) into buf^1;
//         p4 -> A-lo(tS2) into buf (safe: buf's A last read in p3).
// vmcnt(2) at group end: all but the newest 2 loads (p4's A-lo) landed.
#define GRP(bf, tS1, tS2) { \
  a0=RD_A(bf,0,c0); a1=RD_A(bf,1,c0); a2=RD_A(bf,2,c0); a3=RD_A(bf,3,c0); \
  a4=RD_A(bf,4,c0); a5=RD_A(bf,5,c0); a6=RD_A(bf,6,c0); a7=RD_A(bf,7,c0); \
  b0=RD_B(bf,0,c0); b1=RD_B(bf,1,c0); \
  STG(Ab, lda, lsA, 1-(bf), 1, tS1); STG(Bb, ldb, lsB, 1-(bf), 0, tS1); \
  BAR(); PRIO(1); MM8(0, b0); MM8(1, b1); PRIO(0); BAR(); \
  b2=RD_B(bf,2,c0); b3=RD_B(bf,3,c0); \
  STG(Bb, ldb, lsB, 1-(bf), 1, tS1); \
  BAR(); PRIO(1); MM8(2, b2); MM8(3, b3); PRIO(0); BAR(); \
  a0=RD_A(bf,0,c1); a1=RD_A(bf,1,c1); a2=RD_A(bf,2,c1); a3=RD_A(bf,3,c1); \
  a4=RD_A(bf,4,c1); a5=RD_A(bf,5,c1); a6=RD_A(bf,6,c1); a7=RD_A(bf,7,c1); \
  b0=RD_B(bf,0,c1); b1=RD_B(bf,1,c1); \
  BAR(); PRIO(1); MM8(0, b0); MM8(1, b1); PRIO(0); BAR(); \
  b2=RD_B(bf,2,c1); b3=RD_B(bf,3,c1); \
  STG(Ab, lda, lsA, (bf), 0, tS2); \
  BAR(); PRIO(1); MM8(2, b2); MM8(3, b3); PRIO(0); \
  asm volatile("s_waitcnt vmcnt(2)" ::: "memory"); \
  BAR(); }

template<int CMODE, bool RELU>
__global__ __launch_bounds__(512, 2) void mfma256_8ph(
    const ushort_t* __restrict__ A, const ushort_t* __restrict__ B,
    void* __restrict__ Cv, int lda, int ldb, int ldc,
    int K, int zsplit, size_t zA, size_t zB, size_t zC,
    int bShift, size_t bHead, int Mvalid, float scale)
{
  __shared__ ushort_t lsA[2][16384];   // 2 x 32 KB
  __shared__ ushort_t lsB[2][16384];   // 2 x 32 KB  (128 KiB total)
  const int t = threadIdx.x;
  // bijective XCD-aware swizzle (m204)
  const int gx = gridDim.x;
  const int nwg = gx * gridDim.y;
  const int bid = blockIdx.y * gx + blockIdx.x;
  const int qq = nwg >> 3, rr_ = nwg & 7;
  const int xcd = bid & 7, idx = bid >> 3;
  const int swz = (xcd < rr_ ? xcd * (qq + 1) : rr_ * (qq + 1) + (xcd - rr_) * qq) + idx;
  const int m0 = (swz / gx) * 256;
  const int n0 = (swz % gx) * 256;
  const int z = blockIdx.z;
  int Kc = K, kOff = 0;
  size_t aZ = 0, bZ = 0, cZ = 0;
  if (zsplit > 1) { Kc = K / zsplit; kOff = z * Kc; }
  else { aZ = (size_t)z * zA; bZ = (size_t)z * zB; cZ = (size_t)z * zC; }
  const ushort_t* Ab = A + aZ + (size_t)m0 * lda + kOff;
  const ushort_t* Bb = B + bZ + (size_t)n0 * ldb + kOff
                     + (bShift >= 0 ? (size_t)(m0 >> bShift) * bHead : 0);
  const int NT = Kc / 64;         // K-tiles of 64 (NT even, >= 2)

  f32x4 acc[8][4];
  #pragma unroll
  for (int i = 0; i < 8; ++i)
    #pragma unroll
    for (int j = 0; j < 4; ++j) acc[i][j] = (f32x4){0.f, 0.f, 0.f, 0.f};

  const int lane = t & 63;
  const int wv = t >> 6;
  const int wr = (wv >> 2) * 128;   // wave M offset (2 rows of waves)
  const int wc = (wv & 3) * 64;     // wave N offset (4 cols of waves)
  const int lr = lane & 15;
  const int kc = lane >> 4;         // 16B chunk within one k-step
  const int sw = lane & 7;
  const int c0 = (kc ^ sw) * 16;    // swizzled chunk byte, k-step 0
  const int c1 = c0 ^ 64;           // k-step 1 (logical chunk +4)
  const int arow = (wr + lr) * 128;
  const int brow = (wc + lr) * 128;
  const char* lsAc = (const char*)lsA;
  const char* lsBc = (const char*)lsB;

  short8 a0, a1, a2, a3, a4, a5, a6, a7, b0, b1, b2, b3;

  // prologue: tile 0 fully into buf0, A-lo(tile 1) into buf1; verify tile 0.
  STG(Ab, lda, lsA, 0, 0, 0); STG(Ab, lda, lsA, 0, 1, 0);
  STG(Bb, ldb, lsB, 0, 0, 0); STG(Bb, ldb, lsB, 0, 1, 0);
  STG(Ab, lda, lsA, 1, 0, 1);
  asm volatile("s_waitcnt vmcnt(2)" ::: "memory");
  BAR();

  const int NITER = NT >> 1;
  for (int it = 0; it < NITER; ++it) {
    const int tb = 2 * it;
    const int s1 = tb + 1;                       // always < NT
    const int s2 = (tb + 2 < NT) ? tb + 2 : 0;   // clamped (redundant stage on tail)
    const int s3 = (tb + 3 < NT) ? tb + 3 : 0;
    GRP(0, s1, s2)
    GRP(1, s2, s3)
  }

  const int row4 = (lane >> 4) * 4;
  const int coln = lane & 15;
  float* Cf = (float*)Cv + cZ;
  ushort_t* Ch = (ushort_t*)Cv + cZ;
  #pragma unroll
  for (int m = 0; m < 8; ++m) {
    #pragma unroll
    for (int r = 0; r < 4; ++r) {
      const int gm = m0 + wr + m * 16 + row4 + r;
      if (gm < Mvalid) {
        #pragma unroll
        for (int n = 0; n < 4; ++n) {
          const int gn = n0 + wc + n * 16 + coln;
          float v = acc[m][n][r] * scale;
          if (RELU) v = fmaxf(v, 0.f);
          if (CMODE == 0)      Cf[(size_t)gm * ldc + gn] = v;
          else if (CMODE == 1) Ch[(size_t)gm * ldc + gn] = f2bf(v);
          else                 atomicAdd(&Cf[(size_t)gm * ldc + gn], v);
        }
      }
    }
  }
}

#undef GRP
#undef STG
#undef MM8
#undef RD_A
#undef RD_B

// ================= 128x128-tile MFMA GEMM (R2-proven), 256 threads =========
// Extended: z-batch offsets (zA/zB/zC when Ksplit==1), per-m-tile head select
// (bShift/bHead on B), masked M-validity (mMask: valid iff (gm&mMask)<Mvalid).
template<int CMODE, bool RELU>
__global__ __launch_bounds__(256) void mfma_bt(
    const ushort_t* __restrict__ A, const ushort_t* __restrict__ B,
    void* __restrict__ Cv, int lda, int ldb, int ldc,
    int K, int Ksplit, size_t zA, size_t zB, size_t zC,
    int bShift, size_t bHead, int mMask, int Mvalid, float scale)
{
  __shared__ ushort_t lsA[2][128 * 32];
  __shared__ ushort_t lsB[2][128 * 32];
  const int t  = threadIdx.x;
  const int m0 = blockIdx.y * 128;
  const int n0 = blockIdx.x * 128;
  const int z = blockIdx.z;
  int Kc = K, kOff = 0;
  size_t aZ = 0, bZ = 0, cZ = 0;
  if (Ksplit > 1) { Kc = K / Ksplit; kOff = z * Kc; }
  else { aZ = (size_t)z * zA; bZ = (size_t)z * zB; cZ = (size_t)z * zC; }
  const int NT = Kc / 32;
  const ushort_t* Ab = A + aZ + (size_t)m0 * lda + kOff;
  const ushort_t* Bb = B + bZ + (size_t)n0 * ldb + kOff
                     + (bShift >= 0 ? (size_t)(m0 >> bShift) * bHead : 0);
  const int cs = t & 3;

  f32x4 acc[4][4];
  #pragma unroll
  for (int i = 0; i < 4; ++i)
    #pragma unroll
    for (int j = 0; j < 4; ++j) acc[i][j] = (f32x4){0.f, 0.f, 0.f, 0.f};

  const int lane = t & 63;
  const int wv = t >> 6;
  const int wr = (wv >> 1) * 64;
  const int wc = (wv & 1) * 64;
  const int lr = lane & 15;
  const int kc = lane >> 4;

  int roffA[4], roffB[4];
  #pragma unroll
  for (int m = 0; m < 4; ++m) {
    int ra = wr + m * 16 + lr;
    roffA[m] = ra * 64 + ((kc ^ (ra & 3)) * 16);
    int rb = wc + m * 16 + lr;
    roffB[m] = rb * 64 + ((kc ^ (rb & 3)) * 16);
  }

  auto stage = [&](int buf, int kt) {
    const ushort_t* As = Ab + kt * 32;
    const ushort_t* Bs = Bb + kt * 32;
    #pragma unroll
    for (int i = 0; i < 2; ++i) {
      int s = t + i * 256;
      int r = s >> 2;
      int c = cs ^ (r & 3);
      __builtin_amdgcn_global_load_lds(
          (const __attribute__((address_space(1))) u32*)(As + (size_t)r * lda + c * 8),
          (__attribute__((address_space(3))) u32*)(&lsA[buf][s * 8]), 16, 0, 0);
    }
    #pragma unroll
    for (int i = 0; i < 2; ++i) {
      int s = t + i * 256;
      int r = s >> 2;
      int c = cs ^ (r & 3);
      __builtin_amdgcn_global_load_lds(
          (const __attribute__((address_space(1))) u32*)(Bs + (size_t)r * ldb + c * 8),
          (__attribute__((address_space(3))) u32*)(&lsB[buf][s * 8]), 16, 0, 0);
    }
  };

  stage(0, 0);
  __syncthreads();
  int cur = 0;
  for (int kt = 0; kt < NT; ++kt) {
    if (kt + 1 < NT) stage(cur ^ 1, kt + 1);
    short8 af[4], bfr[4];
    const char* baseA = (const char*)&lsA[cur][0];
    const char* baseB = (const char*)&lsB[cur][0];
    #pragma unroll
    for (int m = 0; m < 4; ++m) af[m]  = *(const short8*)(baseA + roffA[m]);
    #pragma unroll
    for (int n = 0; n < 4; ++n) bfr[n] = *(const short8*)(baseB + roffB[n]);
    #pragma unroll
    for (int m = 0; m < 4; ++m)
      #pragma unroll
      for (int n = 0; n < 4; ++n)
        acc[m][n] = __builtin_amdgcn_mfma_f32_16x16x32_bf16(af[m], bfr[n], acc[m][n], 0, 0, 0);
    __syncthreads();
    cur ^= 1;
  }

  const int row4 = (lane >> 4) * 4;
  const int coln = lane & 15;
  float* Cf = (float*)Cv + cZ;
  ushort_t* Ch = (ushort_t*)Cv + cZ;
  #pragma unroll
  for (int m = 0; m < 4; ++m) {
    #pragma unroll
    for (int r = 0; r < 4; ++r) {
      const int gm = m0 + wr + m * 16 + row4 + r;
      const bool ok = (mMask >= 0) ? ((gm & mMask) < Mvalid) : (gm < Mvalid);
      if (ok) {
        #pragma unroll
        for (int n = 0; n < 4; ++n) {
          const int gn = n0 + wc + n * 16 + coln;
          float v = acc[m][n][r] * scale;
          if (RELU) v = fmaxf(v, 0.f);
          if (CMODE == 0)      Cf[(size_t)gm * ldc + gn] = v;
          else if (CMODE == 1) Ch[(size_t)gm * ldc + gn] = f2bf(v);
          else                 atomicAdd(&Cf[(size_t)gm * ldc + gn], v);
        }
      }
    }
  }
}

// ---------------- weights: dst[Mp,Kp] bf16 = W^T (+ bias slot at k==Kv) ----
__global__ __launch_bounds__(256) void wt_conv(
    const float* __restrict__ W, const float* __restrict__ bias,
    ushort_t* __restrict__ dst, int Mtot, int ldw, int Kv, int Kp,
    int PADH, int VALH)
{
  const int m = blockIdx.x;
  const int h = m / PADH, c0 = m % PADH;
  const int fout = h * VALH + c0;
  const bool valid = (c0 < VALH) && (fout < Mtot);
  for (int k = threadIdx.x; k < Kp; k += blockDim.x) {
    float v = 0.f;
    if (valid) {
      if (k < Kv) v = W[(size_t)k * ldw + fout];
      else if (k == Kv) v = bias[fout];
    }
    dst[(size_t)m * Kp + k] = f2bf(v);
  }
}

// ---------------- transpose fp32 [Kv,4096] -> bf16 [4096,Kp], bias slot ----
__global__ __launch_bounds__(256) void trans_pad(
    const float* __restrict__ src, ushort_t* __restrict__ dst, int Kv, int Kp)
{
  __shared__ float tl[64][65];
  const int t = threadIdx.x;
  const int f0 = blockIdx.x * 64;
  const int i0 = blockIdx.y * 64;
  const int c = t & 63, rbase = t >> 6;
  #pragma unroll
  for (int it = 0; it < 16; ++it) {
    int r = rbase + it * 4;
    int f = f0 + r;
    tl[r][c] = (f < Kv) ? src[(size_t)f * 4096 + i0 + c] : 0.f;
  }
  __syncthreads();
  #pragma unroll
  for (int it = 0; it < 16; ++it) {
    int r = rbase + it * 4;
    int f = f0 + c;
    if (f < Kp) {
      float v = (f < Kv) ? tl[c][r] : ((f == Kv) ? 1.f : 0.f);
      dst[(size_t)(i0 + r) * Kp + f] = f2bf(v);
    }
  }
}

// ---------------- row softmax, bf16 in/out, in place, 4096 cols ------------
__global__ __launch_bounds__(256) void softmax_bf16(ushort_t* __restrict__ S)
{
  __shared__ float red[4];
  const int t = threadIdx.x;
  uint4* row = (uint4*)(S + (size_t)blockIdx.x * 4096);
  uint4 d0 = row[t], d1 = row[t + 256];
  float v[16];
  {
    const u32* u = (const u32*)&d0;
    #pragma unroll
    for (int q = 0; q < 4; ++q) {
      v[q * 2]     = __uint_as_float((u[q] & 0xffffu) << 16);
      v[q * 2 + 1] = __uint_as_float(u[q] & 0xffff0000u);
    }
    const u32* w = (const u32*)&d1;
    #pragma unroll
    for (int q = 0; q < 4; ++q) {
      v[8 + q * 2]     = __uint_as_float((w[q] & 0xffffu) << 16);
      v[8 + q * 2 + 1] = __uint_as_float(w[q] & 0xffff0000u);
    }
  }
  float mx = v[0];
  #pragma unroll
  for (int e = 1; e < 16; ++e) mx = fmaxf(mx, v[e]);
  mx = block_max256(mx, red);
  float sum = 0.f;
  #pragma unroll
  for (int e = 0; e < 16; ++e) { v[e] = __expf(v[e] - mx); sum += v[e]; }
  sum = block_sum256(sum, red);
  const float inv = 1.f / sum;
  u32 o0[4], o1[4];
  #pragma unroll
  for (int q = 0; q < 4; ++q) {
    o0[q] = (u32)f2bf(v[q * 2] * inv) | ((u32)f2bf(v[q * 2 + 1] * inv) << 16);
    o1[q] = (u32)f2bf(v[8 + q * 2] * inv) | ((u32)f2bf(v[8 + q * 2 + 1] * inv) << 16);
  }
  row[t]       = *(uint4*)o0;
  row[t + 256] = *(uint4*)o1;
}

// ---------------- GraphNorm per feature row over 4096 nodes ----------------
// padH>0: source row mapping r -> (r/valH)*padH + r%valH (head-padded input).
template<bool L2NORM, bool BF16OUT>
__global__ __launch_bounds__(256) void graph_norm_rows(
    const float* __restrict__ X, void* __restrict__ Yv,
    const float* __restrict__ w, const float* __restrict__ b,
    const float* __restrict__ ms, int padH, int valH)
{
  __shared__ float red[4];
  const int t = threadIdx.x;
  const int row = blockIdx.x;
  const int pr = padH ? (row / valH) * padH + row % valH : row;
  const float* x = X + (size_t)pr * 4096;
  float v[16];
  float s = 0.f;
  #pragma unroll
  for (int e = 0; e < 4; ++e) {
    *(float4*)&v[e * 4] = *(const float4*)&x[t * 4 + 1024 * e];
    #pragma unroll
    for (int q = 0; q < 4; ++q) s += v[e * 4 + q];
  }
  const float mean = block_sum256(s, red) * (1.f / 4096.f);
  const float sub = mean * ms[row];
  float s2 = 0.f;
  #pragma unroll
  for (int e = 0; e < 16; ++e) { v[e] -= sub; s2 += v[e] * v[e]; }
  const float var = block_sum256(s2, red) * (1.f / 4096.f);
  const float scl = rsqrtf(var + 1e-5f) * w[row];
  const float bb = b[row];
  #pragma unroll
  for (int e = 0; e < 16; ++e) v[e] = v[e] * scl + bb;
  float osc = 1.f;
  if (L2NORM) {
    float s3 = 0.f;
    #pragma unroll
    for (int e = 0; e < 16; ++e) s3 += v[e] * v[e];
    osc = rsqrtf(block_sum256(s3, red));
  }
  if (BF16OUT) {
    ushort_t* y = (ushort_t*)Yv + (size_t)row * 4096;
    #pragma unroll
    for (int e = 0; e < 4; ++e) {
      ushort_t o0[4];
      #pragma unroll
      for (int q = 0; q < 4; ++q) o0[q] = f2bf(v[e * 4 + q] * osc);
      *(ushort2*)&y[t * 4 + 1024 * e] = *(ushort2*)&o0[0];
      *(ushort2*)&y[t * 4 + 1024 * e + 2] = *(ushort2*)&o0[2];
    }
  } else {
    float* y = (float*)Yv + (size_t)row * 4096;
    #pragma unroll
    for (int e = 0; e < 4; ++e) {
      float o0[4];
      #pragma unroll
      for (int q = 0; q < 4; ++q) o0[q] = v[e * 4 + q] * osc;
      *(float4*)&y[t * 4 + 1024 * e] = *(float4*)&o0[0];
    }
  }
}

// ---------------- in-place relu over float4s -------------------------------
__global__ __launch_bounds__(256) void relu_inplace(float* __restrict__ p)
{
  const size_t i = (size_t)blockIdx.x * 256 + threadIdx.x;
  float4 v = ((float4*)p)[i];
  v.x = fmaxf(v.x, 0.f); v.y = fmaxf(v.y, 0.f);
  v.z = fmaxf(v.z, 0.f); v.w = fmaxf(v.w, 0.f);
  ((float4*)p)[i] = v;
}

extern "C" void kernel_launch(void* const* d_in, const int* in_sizes, int n_in,
                              void* d_out, int out_size, void* d_ws, size_t ws_size,
                              hipStream_t stream)
{
  (void)in_sizes; (void)n_in; (void)out_size; (void)ws_size;
  const float* lr_x = (const float*)d_in[0];
  const float* Wq1 = (const float*)d_in[1];  const float* bq1 = (const float*)d_in[2];
  const float* Wk1 = (const float*)d_in[3];  const float* bk1 = (const float*)d_in[4];
  const float* Wv1 = (const float*)d_in[5];  const float* bv1 = (const float*)d_in[6];
  const float* Ws1 = (const float*)d_in[7];  const float* bs1 = (const float*)d_in[8];
  const float* gn1w = (const float*)d_in[9]; const float* gn1b = (const float*)d_in[10];
  const float* gn1ms = (const float*)d_in[11];
  const float* Wq2 = (const float*)d_in[12]; const float* bq2 = (const float*)d_in[13];
  const float* Wk2 = (const float*)d_in[14]; const float* bk2 = (const float*)d_in[15];
  const float* Wv2 = (const float*)d_in[16]; const float* bv2 = (const float*)d_in[17];
  const float* Ws2 = (const float*)d_in[18]; const float* bs2 = (const float*)d_in[19];
  const float* gn2w = (const float*)d_in[20]; const float* gn2b = (const float*)d_in[21];
  const float* gn2ms = (const float*)d_in[22];

  char* p = (char*)d_ws;
  auto alloc = [&](size_t bytes) { char* r = p; p += (bytes + 255) & ~(size_t)255; return r; };
  const size_t PSTR = (size_t)4096 * 4096;                      // elements per P matrix
  ushort_t* Pall = (ushort_t*)alloc(PSTR * 4 * 2);              // 4 x [4096,4096] bf16
  ushort_t* xb   = (ushort_t*)alloc((size_t)4096 * 544 * 2);
  ushort_t* qk1b = (ushort_t*)alloc((size_t)4096 * 512 * 2);    // [4096, 4h*64(q)|4h*64(k)]
  ushort_t* v1b  = (ushort_t*)alloc((size_t)512 * 4096 * 2);    // [4h*128, 4096]
  float*    s1p  = (float*)   alloc((size_t)512 * 4096 * 4);    // head-padded skip+attn
  float*    h1nT = (float*)   alloc((size_t)200 * 4096 * 4);
  ushort_t* h1nb = (ushort_t*)alloc((size_t)4096 * 256 * 2);    // h1n^T + bias, Kp=256
  ushort_t* Wqk1 = (ushort_t*)alloc((size_t)512 * 544 * 2);
  ushort_t* Wv1b = (ushort_t*)alloc((size_t)512 * 544 * 2);
  ushort_t* Ws1p = (ushort_t*)alloc((size_t)512 * 544 * 2);
  ushort_t* Wqk2 = (ushort_t*)alloc((size_t)4096 * 256 * 2);
  ushort_t* Wv2b = (ushort_t*)alloc((size_t)2048 * 256 * 2);
  ushort_t* Ws2b = (ushort_t*)alloc((size_t)2048 * 256 * 2);
  ushort_t* qk2b = (ushort_t*)alloc((size_t)4096 * 4096 * 2);   // [4096, 2048(q)|2048(k)]
  ushort_t* v2T  = (ushort_t*)alloc((size_t)2048 * 4096 * 2);
  float*    s2T  = (float*)   alloc((size_t)2048 * 4096 * 4);
  ushort_t* h2b  = (ushort_t*)alloc((size_t)2048 * 4096 * 2);

  const dim3 b256(256, 1, 1);
  const dim3 b512(512, 1, 1);
  const float sc1 = 0.14142135623730951f;  // 1/sqrt(50)
  const float sc2 = 0.04419417382415922f;  // 1/sqrt(512)

  // ---- weight conversions (layer1 Kp=544, layer2 Kp=256, bias at k==Kv)
  wt_conv<<<dim3(256),  b256, 0, stream>>>(Wq1, bq1, Wqk1,             200, 200, 512, 544, 64, 50);
  wt_conv<<<dim3(256),  b256, 0, stream>>>(Wk1, bk1, Wqk1 + 256 * 544, 200, 200, 512, 544, 64, 50);
  wt_conv<<<dim3(512),  b256, 0, stream>>>(Wv1, bv1, Wv1b,             200, 200, 512, 544, 128, 50);
  wt_conv<<<dim3(512),  b256, 0, stream>>>(Ws1, bs1, Ws1p,             200, 200, 512, 544, 128, 50);
  wt_conv<<<dim3(2048), b256, 0, stream>>>(Wq2, bq2, Wqk2,              2048, 2048, 200, 256, 2048, 2048);
  wt_conv<<<dim3(2048), b256, 0, stream>>>(Wk2, bk2, Wqk2 + 2048 * 256, 2048, 2048, 200, 256, 2048, 2048);
  wt_conv<<<dim3(2048), b256, 0, stream>>>(Wv2, bv2, Wv2b,              2048, 2048, 200, 256, 2048, 2048);
  wt_conv<<<dim3(2048), b256, 0, stream>>>(Ws2, bs2, Ws2b,              2048, 2048, 200, 256, 2048, 2048);
  trans_pad<<<dim3(9, 64), b256, 0, stream>>>(lr_x, xb, 512, 544);

  // ---- layer-1 projections (128^2 kernel)
  mfma_bt<1, false><<<dim3(4, 32), b256, 0, stream>>>(
      xb, Wqk1, qk1b, 544, 544, 512, 544, 1, 0, 0, 0, -1, 0, -1, 4096, 1.f);
  mfma_bt<1, false><<<dim3(32, 4), b256, 0, stream>>>(
      Wv1b, xb, v1b, 544, 544, 4096, 544, 1, 0, 0, 0, -1, 0, -1, 512, 1.f);
  mfma_bt<0, false><<<dim3(32, 4), b256, 0, stream>>>(
      Ws1p, xb, s1p, 544, 544, 4096, 544, 1, 0, 0, 0, -1, 0, 127, 50, 1.f);

  // ---- attention 1 (C=50, Kpad=64): batched scores -> softmax -> batched PV
  mfma_bt<1, false><<<dim3(32, 32, 4), b256, 0, stream>>>(
      qk1b, qk1b + 256, Pall, 512, 512, 4096, 64, 1,
      64, 64, PSTR, -1, 0, -1, 4096, sc1);
  softmax_bf16<<<dim3(16384), b256, 0, stream>>>(Pall);
  mfma_bt<2, false><<<dim3(32, 4, 8), b256, 0, stream>>>(
      v1b, Pall, s1p, 4096, 4096, 4096, 4096, 8,
      0, 0, 0, 7, PSTR, 127, 50, 1.f);
  graph_norm_rows<false, false><<<dim3(200), b256, 0, stream>>>(
      s1p, h1nT, gn1w, gn1b, gn1ms, 128, 50);
  trans_pad<<<dim3(4, 64), b256, 0, stream>>>(h1nT, h1nb, 200, 256);

  // ---- layer-2 projections (8-phase 256^2 kernel, K=256)
  mfma256_8ph<1, false><<<dim3(16, 16), b512, 0, stream>>>(
      h1nb, Wqk2, qk2b, 256, 256, 4096, 256, 1, 0, 0, 0, -1, 0, 4096, 1.f);
  mfma256_8ph<1, false><<<dim3(16, 8), b512, 0, stream>>>(
      Wv2b, h1nb, v2T, 256, 256, 4096, 256, 1, 0, 0, 0, -1, 0, 2048, 1.f);
  mfma256_8ph<0, false><<<dim3(16, 8), b512, 0, stream>>>(
      Ws2b, h1nb, s2T, 256, 256, 4096, 256, 1, 0, 0, 0, -1, 0, 2048, 1.f);

  // ---- attention 2: scores all heads (z-batch) -> softmax -> PV (batched)
  mfma256_8ph<1, false><<<dim3(16, 16, 4), b512, 0, stream>>>(
      qk2b, qk2b + 2048, Pall, 4096, 4096, 4096, 512, 1,
      512, 512, PSTR, -1, 0, 4096, sc2);
  softmax_bf16<<<dim3(16384), b256, 0, stream>>>(Pall);
  mfma256_8ph<2, false><<<dim3(16, 8, 2), b512, 0, stream>>>(
      v2T, Pall, s2T, 4096, 4096, 4096, 4096, 2,
      0, 0, 0, 9, PSTR, 2048, 1.f);

  // ---- gn2 + row L2 normalize -> h2b (bf16)
  graph_norm_rows<true, true><<<dim3(2048), b256, 0, stream>>>(
      s2T, h2b, gn2w, gn2b, gn2ms, 0, 0);

  // ---- out = relu(h2n . h2n^T): split-K atomic into zeroed d_out, then relu
  hipMemsetAsync(d_out, 0, (size_t)2048 * 2048 * 4, stream);
  mfma256_8ph<2, false><<<dim3(8, 8, 4), b512, 0, stream>>>(
      h2b, h2b, d_out, 4096, 4096, 2048, 4096, 4,
      0, 0, 0, -1, 0, 2048, 1.f);
  relu_inplace<<<dim3(4096), b256, 0, stream>>>((float*)d_out);
}

// Round 6
// 530.943 us; speedup vs baseline: 12.1245x; 1.2238x over previous
//
#include <hip/hip_runtime.h>
#include <math.h>

typedef unsigned int u32;
typedef unsigned short ushort_t;
typedef __attribute__((ext_vector_type(8))) short short8;
typedef __attribute__((ext_vector_type(4))) float f32x4;

__device__ __forceinline__ ushort_t f2bf(float x) {
  u32 u = __float_as_uint(x);
  u32 r = (u + 0x7fffu + ((u >> 16) & 1u)) >> 16;
  return (ushort_t)r;
}
__device__ __forceinline__ float bf2f(u32 s) {
  return __uint_as_float(s << 16);
}
__device__ __forceinline__ void ld4bf(const ushort_t* p, float* o) {
  uint2 u = *(const uint2*)p;
  o[0] = bf2f(u.x & 0xffffu); o[1] = bf2f(u.x >> 16);
  o[2] = bf2f(u.y & 0xffffu); o[3] = bf2f(u.y >> 16);
}

// ---------------- block reduction helpers (256 threads = 4 waves) ----------
__device__ __forceinline__ float block_sum256(float v, float* red) {
  #pragma unroll
  for (int o = 32; o > 0; o >>= 1) v += __shfl_down(v, o, 64);
  __syncthreads();
  if ((threadIdx.x & 63) == 0) red[threadIdx.x >> 6] = v;
  __syncthreads();
  return red[0] + red[1] + red[2] + red[3];
}

// =====================================================================
// 256x256-tile, 8-phase, counted-vmcnt MFMA GEMM (m201-style schedule).
// C[m,n] (op)= scale * sum_k A[m,k]*B[n,k];  A:[M,K] bf16, B:[N,K] bf16.
// BK=64, K/zsplit % 128 == 0. 512 thr = 8 waves (2M x 4N), 128 KiB LDS.
// zsplit>1: grid.z = K-split, C += z*zC. zsplit==1: grid.z = batch (zA/zB/zC).
// bShift>=0: B += (m0>>bShift)*bHead (per-m-tile head select).
// CMODE: 0 = store f32 (+RELU), 1 = store bf16, 2 = atomicAdd f32.
// EXPSUM: v=exp(v*scale) before store; row-sums atomically added to Rs[z*4096+gm].
// =====================================================================
#define RD_A(bb, mm, cc) (*(const short8*)(lsAc + (bb)*32768 + arow + (mm)*2048 + (cc)))
#define RD_B(bb, nn, cc) (*(const short8*)(lsBc + (bb)*32768 + brow + (nn)*2048 + (cc)))

#define MM8(nn, bv) { \
  acc[0][nn] = __builtin_amdgcn_mfma_f32_16x16x32_bf16(a0, bv, acc[0][nn], 0,0,0); \
  acc[1][nn] = __builtin_amdgcn_mfma_f32_16x16x32_bf16(a1, bv, acc[1][nn], 0,0,0); \
  acc[2][nn] = __builtin_amdgcn_mfma_f32_16x16x32_bf16(a2, bv, acc[2][nn], 0,0,0); \
  acc[3][nn] = __builtin_amdgcn_mfma_f32_16x16x32_bf16(a3, bv, acc[3][nn], 0,0,0); \
  acc[4][nn] = __builtin_amdgcn_mfma_f32_16x16x32_bf16(a4, bv, acc[4][nn], 0,0,0); \
  acc[5][nn] = __builtin_amdgcn_mfma_f32_16x16x32_bf16(a5, bv, acc[5][nn], 0,0,0); \
  acc[6][nn] = __builtin_amdgcn_mfma_f32_16x16x32_bf16(a6, bv, acc[6][nn], 0,0,0); \
  acc[7][nn] = __builtin_amdgcn_mfma_f32_16x16x32_bf16(a7, bv, acc[7][nn], 0,0,0); }

#define STG(BASE, LD, LS, bb, hf, tt) { \
  _Pragma("unroll") \
  for (int ii = 0; ii < 2; ++ii) { \
    const int s_ = t + ii * 512; \
    const int r_ = s_ >> 3; \
    const int lc_ = (s_ & 7) ^ (r_ & 7); \
    __builtin_amdgcn_global_load_lds( \
      (const __attribute__((address_space(1))) u32*)((BASE) + (size_t)((hf) * 128 + r_) * (LD) + (size_t)(tt) * 64 + lc_ * 8), \
      (__attribute__((address_space(3))) u32*)(&(LS)[bb][(hf) * 8192 + s_ * 8]), 16, 0, 0); \
  } }

#define BAR() __builtin_amdgcn_s_barrier()
#define PRIO(x) __builtin_amdgcn_s_setprio(x)

#define GRP(bf, tS1, tS2) { \
  a0=RD_A(bf,0,c0); a1=RD_A(bf,1,c0); a2=RD_A(bf,2,c0); a3=RD_A(bf,3,c0); \
  a4=RD_A(bf,4,c0); a5=RD_A(bf,5,c0); a6=RD_A(bf,6,c0); a7=RD_A(bf,7,c0); \
  b0=RD_B(bf,0,c0); b1=RD_B(bf,1,c0); \
  STG(Ab, lda, lsA, 1-(bf), 1, tS1); STG(Bb, ldb, lsB, 1-(bf), 0, tS1); \
  BAR(); PRIO(1); MM8(0, b0); MM8(1, b1); PRIO(0); BAR(); \
  b2=RD_B(bf,2,c0); b3=RD_B(bf,3,c0); \
  STG(Bb, ldb, lsB, 1-(bf), 1, tS1); \
  BAR(); PRIO(1); MM8(2, b2); MM8(3, b3); PRIO(0); BAR(); \
  a0=RD_A(bf,0,c1); a1=RD_A(bf,1,c1); a2=RD_A(bf,2,c1); a3=RD_A(bf,3,c1); \
  a4=RD_A(bf,4,c1); a5=RD_A(bf,5,c1); a6=RD_A(bf,6,c1); a7=RD_A(bf,7,c1); \
  b0=RD_B(bf,0,c1); b1=RD_B(bf,1,c1); \
  BAR(); PRIO(1); MM8(0, b0); MM8(1, b1); PRIO(0); BAR(); \
  b2=RD_B(bf,2,c1); b3=RD_B(bf,3,c1); \
  STG(Ab, lda, lsA, (bf), 0, tS2); \
  BAR(); PRIO(1); MM8(2, b2); MM8(3, b3); PRIO(0); \
  asm volatile("s_waitcnt vmcnt(2)" ::: "memory"); \
  BAR(); }

template<int CMODE, bool RELU, bool EXPSUM>
__global__ __launch_bounds__(512, 2) void mfma256_8ph(
    const ushort_t* __restrict__ A, const ushort_t* __restrict__ B,
    void* __restrict__ Cv, int lda, int ldb, int ldc,
    int K, int zsplit, size_t zA, size_t zB, size_t zC,
    int bShift, size_t bHead, int Mvalid, float scale,
    float* __restrict__ Rs)
{
  __shared__ ushort_t lsA[2][16384];
  __shared__ ushort_t lsB[2][16384];
  const int t = threadIdx.x;
  const int gx = gridDim.x;
  const int nwg = gx * gridDim.y;
  const int bid = blockIdx.y * gx + blockIdx.x;
  const int qq = nwg >> 3, rr_ = nwg & 7;
  const int xcd = bid & 7, idx = bid >> 3;
  const int swz = (xcd < rr_ ? xcd * (qq + 1) : rr_ * (qq + 1) + (xcd - rr_) * qq) + idx;
  const int m0 = (swz / gx) * 256;
  const int n0 = (swz % gx) * 256;
  const int z = blockIdx.z;
  int Kc = K, kOff = 0;
  size_t aZ = 0, bZ = 0, cZ = 0;
  if (zsplit > 1) { Kc = K / zsplit; kOff = z * Kc; cZ = (size_t)z * zC; }
  else { aZ = (size_t)z * zA; bZ = (size_t)z * zB; cZ = (size_t)z * zC; }
  const ushort_t* Ab = A + aZ + (size_t)m0 * lda + kOff;
  const ushort_t* Bb = B + bZ + (size_t)n0 * ldb + kOff
                     + (bShift >= 0 ? (size_t)(m0 >> bShift) * bHead : 0);
  const int NT = Kc / 64;

  f32x4 acc[8][4];
  #pragma unroll
  for (int i = 0; i < 8; ++i)
    #pragma unroll
    for (int j = 0; j < 4; ++j) acc[i][j] = (f32x4){0.f, 0.f, 0.f, 0.f};

  const int lane = t & 63;
  const int wv = t >> 6;
  const int wr = (wv >> 2) * 128;
  const int wc = (wv & 3) * 64;
  const int lr = lane & 15;
  const int kc = lane >> 4;
  const int sw = lane & 7;
  const int c0 = (kc ^ sw) * 16;
  const int c1 = c0 ^ 64;
  const int arow = (wr + lr) * 128;
  const int brow = (wc + lr) * 128;
  const char* lsAc = (const char*)lsA;
  const char* lsBc = (const char*)lsB;

  short8 a0, a1, a2, a3, a4, a5, a6, a7, b0, b1, b2, b3;

  STG(Ab, lda, lsA, 0, 0, 0); STG(Ab, lda, lsA, 0, 1, 0);
  STG(Bb, ldb, lsB, 0, 0, 0); STG(Bb, ldb, lsB, 0, 1, 0);
  STG(Ab, lda, lsA, 1, 0, 1);
  asm volatile("s_waitcnt vmcnt(2)" ::: "memory");
  BAR();

  const int NITER = NT >> 1;
  for (int it = 0; it < NITER; ++it) {
    const int tb = 2 * it;
    const int s1 = tb + 1;
    const int s2 = (tb + 2 < NT) ? tb + 2 : 0;
    const int s3 = (tb + 3 < NT) ? tb + 3 : 0;
    GRP(0, s1, s2)
    GRP(1, s2, s3)
  }

  const int row4 = (lane >> 4) * 4;
  const int coln = lane & 15;
  float* Cf = (float*)Cv + cZ;
  ushort_t* Ch = (ushort_t*)Cv + cZ;
  float* rs = EXPSUM ? (Rs + (size_t)z * 4096) : nullptr;
  #pragma unroll
  for (int m = 0; m < 8; ++m) {
    #pragma unroll
    for (int r = 0; r < 4; ++r) {
      const int gm = m0 + wr + m * 16 + row4 + r;
      const bool ok = gm < Mvalid;
      float rowpart = 0.f;
      #pragma unroll
      for (int n = 0; n < 4; ++n) {
        const int gn = n0 + wc + n * 16 + coln;
        float v = acc[m][n][r] * scale;
        if (EXPSUM) { v = __expf(v); rowpart += v; }
        if (RELU) v = fmaxf(v, 0.f);
        if (ok) {
          if (CMODE == 0)      Cf[(size_t)gm * ldc + gn] = v;
          else if (CMODE == 1) Ch[(size_t)gm * ldc + gn] = f2bf(v);
          else                 atomicAdd(&Cf[(size_t)gm * ldc + gn], v);
        }
      }
      if (EXPSUM) {
        rowpart += __shfl_xor(rowpart, 1);
        rowpart += __shfl_xor(rowpart, 2);
        rowpart += __shfl_xor(rowpart, 4);
        rowpart += __shfl_xor(rowpart, 8);
        if (ok && (lane & 15) == 0) atomicAdd(&rs[gm], rowpart);
      }
    }
  }
}

#undef GRP
#undef STG
#undef MM8
#undef RD_A
#undef RD_B

// ================= 128x128-tile MFMA GEMM, 256 threads =====================
template<int CMODE, bool RELU, bool EXPSUM>
__global__ __launch_bounds__(256) void mfma_bt(
    const ushort_t* __restrict__ A, const ushort_t* __restrict__ B,
    void* __restrict__ Cv, int lda, int ldb, int ldc,
    int K, int Ksplit, size_t zA, size_t zB, size_t zC,
    int bShift, size_t bHead, int mMask, int Mvalid, float scale,
    float* __restrict__ Rs)
{
  __shared__ ushort_t lsA[2][128 * 32];
  __shared__ ushort_t lsB[2][128 * 32];
  const int t  = threadIdx.x;
  const int m0 = blockIdx.y * 128;
  const int n0 = blockIdx.x * 128;
  const int z = blockIdx.z;
  int Kc = K, kOff = 0;
  size_t aZ = 0, bZ = 0, cZ = 0;
  if (Ksplit > 1) { Kc = K / Ksplit; kOff = z * Kc; cZ = (size_t)z * zC; }
  else { aZ = (size_t)z * zA; bZ = (size_t)z * zB; cZ = (size_t)z * zC; }
  const int NT = Kc / 32;
  const ushort_t* Ab = A + aZ + (size_t)m0 * lda + kOff;
  const ushort_t* Bb = B + bZ + (size_t)n0 * ldb + kOff
                     + (bShift >= 0 ? (size_t)(m0 >> bShift) * bHead : 0);
  const int cs = t & 3;

  f32x4 acc[4][4];
  #pragma unroll
  for (int i = 0; i < 4; ++i)
    #pragma unroll
    for (int j = 0; j < 4; ++j) acc[i][j] = (f32x4){0.f, 0.f, 0.f, 0.f};

  const int lane = t & 63;
  const int wv = t >> 6;
  const int wr = (wv >> 1) * 64;
  const int wc = (wv & 1) * 64;
  const int lr = lane & 15;
  const int kc = lane >> 4;

  int roffA[4], roffB[4];
  #pragma unroll
  for (int m = 0; m < 4; ++m) {
    int ra = wr + m * 16 + lr;
    roffA[m] = ra * 64 + ((kc ^ (ra & 3)) * 16);
    int rb = wc + m * 16 + lr;
    roffB[m] = rb * 64 + ((kc ^ (rb & 3)) * 16);
  }

  auto stage = [&](int buf, int kt) {
    const ushort_t* As = Ab + kt * 32;
    const ushort_t* Bs = Bb + kt * 32;
    #pragma unroll
    for (int i = 0; i < 2; ++i) {
      int s = t + i * 256;
      int r = s >> 2;
      int c = cs ^ (r & 3);
      __builtin_amdgcn_global_load_lds(
          (const __attribute__((address_space(1))) u32*)(As + (size_t)r * lda + c * 8),
          (__attribute__((address_space(3))) u32*)(&lsA[buf][s * 8]), 16, 0, 0);
    }
    #pragma unroll
    for (int i = 0; i < 2; ++i) {
      int s = t + i * 256;
      int r = s >> 2;
      int c = cs ^ (r & 3);
      __builtin_amdgcn_global_load_lds(
          (const __attribute__((address_space(1))) u32*)(Bs + (size_t)r * ldb + c * 8),
          (__attribute__((address_space(3))) u32*)(&lsB[buf][s * 8]), 16, 0, 0);
    }
  };

  stage(0, 0);
  __syncthreads();
  int cur = 0;
  for (int kt = 0; kt < NT; ++kt) {
    if (kt + 1 < NT) stage(cur ^ 1, kt + 1);
    short8 af[4], bfr[4];
    const char* baseA = (const char*)&lsA[cur][0];
    const char* baseB = (const char*)&lsB[cur][0];
    #pragma unroll
    for (int m = 0; m < 4; ++m) af[m]  = *(const short8*)(baseA + roffA[m]);
    #pragma unroll
    for (int n = 0; n < 4; ++n) bfr[n] = *(const short8*)(baseB + roffB[n]);
    #pragma unroll
    for (int m = 0; m < 4; ++m)
      #pragma unroll
      for (int n = 0; n < 4; ++n)
        acc[m][n] = __builtin_amdgcn_mfma_f32_16x16x32_bf16(af[m], bfr[n], acc[m][n], 0, 0, 0);
    __syncthreads();
    cur ^= 1;
  }

  const int row4 = (lane >> 4) * 4;
  const int coln = lane & 15;
  float* Cf = (float*)Cv + cZ;
  ushort_t* Ch = (ushort_t*)Cv + cZ;
  float* rs = EXPSUM ? (Rs + (size_t)z * 4096) : nullptr;
  #pragma unroll
  for (int m = 0; m < 4; ++m) {
    #pragma unroll
    for (int r = 0; r < 4; ++r) {
      const int gm = m0 + wr + m * 16 + row4 + r;
      const bool ok = (mMask >= 0) ? ((gm & mMask) < Mvalid) : (gm < Mvalid);
      float rowpart = 0.f;
      #pragma unroll
      for (int n = 0; n < 4; ++n) {
        const int gn = n0 + wc + n * 16 + coln;
        float v = acc[m][n][r] * scale;
        if (EXPSUM) { v = __expf(v); rowpart += v; }
        if (RELU) v = fmaxf(v, 0.f);
        if (ok) {
          if (CMODE == 0)      Cf[(size_t)gm * ldc + gn] = v;
          else if (CMODE == 1) Ch[(size_t)gm * ldc + gn] = f2bf(v);
          else                 atomicAdd(&Cf[(size_t)gm * ldc + gn], v);
        }
      }
      if (EXPSUM) {
        rowpart += __shfl_xor(rowpart, 1);
        rowpart += __shfl_xor(rowpart, 2);
        rowpart += __shfl_xor(rowpart, 4);
        rowpart += __shfl_xor(rowpart, 8);
        if (ok && (lane & 15) == 0) atomicAdd(&rs[gm], rowpart);
      }
    }
  }
}

// ---------------- weights: dst[Mp,Kp] bf16 = W^T (+ bias slot at k==Kv) ----
__global__ __launch_bounds__(256) void wt_conv(
    const float* __restrict__ W, const float* __restrict__ bias,
    ushort_t* __restrict__ dst, int Mtot, int ldw, int Kv, int Kp,
    int PADH, int VALH)
{
  const int m = blockIdx.x;
  const int h = m / PADH, c0 = m % PADH;
  const int fout = h * VALH + c0;
  const bool valid = (c0 < VALH) && (fout < Mtot);
  for (int k = threadIdx.x; k < Kp; k += blockDim.x) {
    float v = 0.f;
    if (valid) {
      if (k < Kv) v = W[(size_t)k * ldw + fout];
      else if (k == Kv) v = bias[fout];
    }
    dst[(size_t)m * Kp + k] = f2bf(v);
  }
}

// ---------------- transpose fp32 [Kv,4096] -> bf16 [4096,Kp], bias slot ----
__global__ __launch_bounds__(256) void trans_pad(
    const float* __restrict__ src, ushort_t* __restrict__ dst, int Kv, int Kp)
{
  __shared__ float tl[64][65];
  const int t = threadIdx.x;
  const int f0 = blockIdx.x * 64;
  const int i0 = blockIdx.y * 64;
  const int c = t & 63, rbase = t >> 6;
  #pragma unroll
  for (int it = 0; it < 16; ++it) {
    int r = rbase + it * 4;
    int f = f0 + r;
    tl[r][c] = (f < Kv) ? src[(size_t)f * 4096 + i0 + c] : 0.f;
  }
  __syncthreads();
  #pragma unroll
  for (int it = 0; it < 16; ++it) {
    int r = rbase + it * 4;
    int f = f0 + c;
    if (f < Kp) {
      float v = (f < Kv) ? tl[c][r] : ((f == Kv) ? 1.f : 0.f);
      dst[(size_t)(i0 + r) * Kp + f] = f2bf(v);
    }
  }
}

// ---------------- GraphNorm layer 1: x = skip + attn/r, gn, f32 out --------
__global__ __launch_bounds__(256) void graph_norm_attn1(
    const float* __restrict__ skip, const float* __restrict__ attn,
    const float* __restrict__ r1, float* __restrict__ out,
    const float* __restrict__ w, const float* __restrict__ b,
    const float* __restrict__ ms)
{
  __shared__ float red[4];
  const int t = threadIdx.x;
  const int row = blockIdx.x;            // 0..199
  const int pr = (row / 50) * 128 + row % 50;
  const float* sk = skip + (size_t)pr * 4096;
  const float* at = attn + (size_t)pr * 4096;
  const float* rr = r1 + (size_t)(row / 50) * 4096;
  float v[16];
  float s = 0.f;
  #pragma unroll
  for (int e = 0; e < 4; ++e) {
    const int idx = t * 4 + 1024 * e;
    float4 a = *(const float4*)&sk[idx];
    float4 o = *(const float4*)&at[idx];
    float4 rv = *(const float4*)&rr[idx];
    v[e*4+0] = a.x + o.x / rv.x; v[e*4+1] = a.y + o.y / rv.y;
    v[e*4+2] = a.z + o.z / rv.z; v[e*4+3] = a.w + o.w / rv.w;
    s += v[e*4+0] + v[e*4+1] + v[e*4+2] + v[e*4+3];
  }
  const float mean = block_sum256(s, red) * (1.f / 4096.f);
  const float sub = mean * ms[row];
  float s2 = 0.f;
  #pragma unroll
  for (int e = 0; e < 16; ++e) { v[e] -= sub; s2 += v[e] * v[e]; }
  const float var = block_sum256(s2, red) * (1.f / 4096.f);
  const float scl = rsqrtf(var + 1e-5f) * w[row];
  const float bb = b[row];
  float* y = out + (size_t)row * 4096;
  #pragma unroll
  for (int e = 0; e < 4; ++e) {
    float o0[4];
    #pragma unroll
    for (int q = 0; q < 4; ++q) o0[q] = v[e * 4 + q] * scl + bb;
    *(float4*)&y[t * 4 + 1024 * e] = *(float4*)&o0[0];
  }
}

// ---------------- GraphNorm layer 2: x = skip + (p0+p1)/r, gn, L2, bf16 ----
__global__ __launch_bounds__(256) void graph_norm_attn2(
    const ushort_t* __restrict__ skip, const ushort_t* __restrict__ p2,
    const float* __restrict__ r2, ushort_t* __restrict__ out,
    const float* __restrict__ w, const float* __restrict__ b,
    const float* __restrict__ ms)
{
  __shared__ float red[4];
  const int t = threadIdx.x;
  const int row = blockIdx.x;            // 0..2047
  const ushort_t* sk = skip + (size_t)row * 4096;
  const ushort_t* pa = p2 + (size_t)row * 4096;
  const ushort_t* pb = p2 + (size_t)2048 * 4096 + (size_t)row * 4096;
  const float* rr = r2 + (size_t)(row >> 9) * 4096;
  float v[16];
  float s = 0.f;
  #pragma unroll
  for (int e = 0; e < 4; ++e) {
    const int idx = t * 4 + 1024 * e;
    float a[4], oa[4], ob[4];
    ld4bf(&sk[idx], a); ld4bf(&pa[idx], oa); ld4bf(&pb[idx], ob);
    float4 rv = *(const float4*)&rr[idx];
    v[e*4+0] = a[0] + (oa[0] + ob[0]) / rv.x;
    v[e*4+1] = a[1] + (oa[1] + ob[1]) / rv.y;
    v[e*4+2] = a[2] + (oa[2] + ob[2]) / rv.z;
    v[e*4+3] = a[3] + (oa[3] + ob[3]) / rv.w;
    s += v[e*4+0] + v[e*4+1] + v[e*4+2] + v[e*4+3];
  }
  const float mean = block_sum256(s, red) * (1.f / 4096.f);
  const float sub = mean * ms[row];
  float s2 = 0.f;
  #pragma unroll
  for (int e = 0; e < 16; ++e) { v[e] -= sub; s2 += v[e] * v[e]; }
  const float var = block_sum256(s2, red) * (1.f / 4096.f);
  const float scl = rsqrtf(var + 1e-5f) * w[row];
  const float bb = b[row];
  #pragma unroll
  for (int e = 0; e < 16; ++e) v[e] = v[e] * scl + bb;
  float s3 = 0.f;
  #pragma unroll
  for (int e = 0; e < 16; ++e) s3 += v[e] * v[e];
  const float osc = rsqrtf(block_sum256(s3, red));
  ushort_t* y = out + (size_t)row * 4096;
  #pragma unroll
  for (int e = 0; e < 4; ++e) {
    ushort_t o0[4];
    #pragma unroll
    for (int q = 0; q < 4; ++q) o0[q] = f2bf(v[e * 4 + q] * osc);
    *(ushort2*)&y[t * 4 + 1024 * e] = *(ushort2*)&o0[0];
    *(ushort2*)&y[t * 4 + 1024 * e + 2] = *(ushort2*)&o0[2];
  }
}

// ---------------- out = relu(g0+g1+g2+g3), float4-wide ---------------------
__global__ __launch_bounds__(256) void add4_relu(
    const float* __restrict__ g, float* __restrict__ out)
{
  const size_t i = (size_t)blockIdx.x * 256 + threadIdx.x;
  const size_t ss = (size_t)2048 * 2048 / 4;
  float4 a = ((const float4*)g)[i];
  float4 b = ((const float4*)g)[i + ss];
  float4 c = ((const float4*)g)[i + 2 * ss];
  float4 d = ((const float4*)g)[i + 3 * ss];
  float4 o;
  o.x = fmaxf(a.x + b.x + c.x + d.x, 0.f);
  o.y = fmaxf(a.y + b.y + c.y + d.y, 0.f);
  o.z = fmaxf(a.z + b.z + c.z + d.z, 0.f);
  o.w = fmaxf(a.w + b.w + c.w + d.w, 0.f);
  ((float4*)out)[i] = o;
}

extern "C" void kernel_launch(void* const* d_in, const int* in_sizes, int n_in,
                              void* d_out, int out_size, void* d_ws, size_t ws_size,
                              hipStream_t stream)
{
  (void)in_sizes; (void)n_in; (void)out_size; (void)ws_size;
  const float* lr_x = (const float*)d_in[0];
  const float* Wq1 = (const float*)d_in[1];  const float* bq1 = (const float*)d_in[2];
  const float* Wk1 = (const float*)d_in[3];  const float* bk1 = (const float*)d_in[4];
  const float* Wv1 = (const float*)d_in[5];  const float* bv1 = (const float*)d_in[6];
  const float* Ws1 = (const float*)d_in[7];  const float* bs1 = (const float*)d_in[8];
  const float* gn1w = (const float*)d_in[9]; const float* gn1b = (const float*)d_in[10];
  const float* gn1ms = (const float*)d_in[11];
  const float* Wq2 = (const float*)d_in[12]; const float* bq2 = (const float*)d_in[13];
  const float* Wk2 = (const float*)d_in[14]; const float* bk2 = (const float*)d_in[15];
  const float* Wv2 = (const float*)d_in[16]; const float* bv2 = (const float*)d_in[17];
  const float* Ws2 = (const float*)d_in[18]; const float* bs2 = (const float*)d_in[19];
  const float* gn2w = (const float*)d_in[20]; const float* gn2b = (const float*)d_in[21];
  const float* gn2ms = (const float*)d_in[22];

  // ---- workspace carve with explicit aliasing (keep total < R4's proven
  // 267 MB; 256 MiB is the suspected cap). Total here: ~242.3 MB.
  char* p = (char*)d_ws;
  auto alloc = [&](size_t bytes) { char* r = p; p += (bytes + 255) & ~(size_t)255; return r; };
  const size_t PSTR = (size_t)4096 * 4096;
  ushort_t* Pall = (ushort_t*)alloc(PSTR * 4 * 2);              // 134.2 MB; Gram partials alias
  ushort_t* xb   = (ushort_t*)alloc((size_t)4096 * 544 * 2);
  ushort_t* qk1b = (ushort_t*)alloc((size_t)4096 * 512 * 2);
  ushort_t* v1b  = (ushort_t*)alloc((size_t)512 * 4096 * 2);
  char*     u0   = alloc((size_t)16 * 1024 * 1024);             // s1p+o1p, later h2b
  float*    s1p  = (float*)u0;                                  // [512,4096] f32 skip
  float*    o1p  = (float*)(u0 + (size_t)8 * 1024 * 1024);      // [512,4096] f32 attn accum
  float*    h1nT = (float*)   alloc((size_t)200 * 4096 * 4);
  ushort_t* h1nb = (ushort_t*)alloc((size_t)4096 * 256 * 2);
  ushort_t* Wqk1 = (ushort_t*)alloc((size_t)512 * 544 * 2);
  ushort_t* Wv1b = (ushort_t*)alloc((size_t)512 * 544 * 2);
  ushort_t* Ws1p = (ushort_t*)alloc((size_t)512 * 544 * 2);
  ushort_t* Wqk2 = (ushort_t*)alloc((size_t)4096 * 256 * 2);
  ushort_t* Wcat = (ushort_t*)alloc((size_t)4096 * 256 * 2);    // [v2 | s2] weights
  ushort_t* qk2b = (ushort_t*)alloc((size_t)4096 * 4096 * 2);   // [node, 2048q|2048k]
  ushort_t* vs2b = (ushort_t*)alloc((size_t)4096 * 4096 * 2);   // rows 0..2047=v2T, 2048..4095=skip2
  float*    r1   = (float*)   alloc((size_t)4 * 4096 * 4);
  float*    r2   = (float*)   alloc((size_t)4 * 4096 * 4);
  // aliases (regions dead by the time the alias is written):
  ushort_t* p2   = qk2b;           // PV-2 partials: qk2b dead after scores-2
  ushort_t* h2b  = (ushort_t*)u0;  // gn2 output: s1p/o1p dead after gn1
  float*    g4   = (float*)Pall;   // Gram partials: Pall dead after PV-2

  const dim3 b256(256, 1, 1);
  const dim3 b512(512, 1, 1);
  const float sc1 = 0.14142135623730951f;  // 1/sqrt(50)
  const float sc2 = 0.04419417382415922f;  // 1/sqrt(512)

  hipMemsetAsync(r1, 0, (size_t)4 * 4096 * 4, stream);
  hipMemsetAsync(r2, 0, (size_t)4 * 4096 * 4, stream);
  hipMemsetAsync(o1p, 0, (size_t)512 * 4096 * 4, stream);

  // ---- weight conversions
  wt_conv<<<dim3(256),  b256, 0, stream>>>(Wq1, bq1, Wqk1,             200, 200, 512, 544, 64, 50);
  wt_conv<<<dim3(256),  b256, 0, stream>>>(Wk1, bk1, Wqk1 + 256 * 544, 200, 200, 512, 544, 64, 50);
  wt_conv<<<dim3(512),  b256, 0, stream>>>(Wv1, bv1, Wv1b,             200, 200, 512, 544, 128, 50);
  wt_conv<<<dim3(512),  b256, 0, stream>>>(Ws1, bs1, Ws1p,             200, 200, 512, 544, 128, 50);
  wt_conv<<<dim3(2048), b256, 0, stream>>>(Wq2, bq2, Wqk2,              2048, 2048, 200, 256, 2048, 2048);
  wt_conv<<<dim3(2048), b256, 0, stream>>>(Wk2, bk2, Wqk2 + 2048 * 256, 2048, 2048, 200, 256, 2048, 2048);
  wt_conv<<<dim3(2048), b256, 0, stream>>>(Wv2, bv2, Wcat,              2048, 2048, 200, 256, 2048, 2048);
  wt_conv<<<dim3(2048), b256, 0, stream>>>(Ws2, bs2, Wcat + 2048 * 256, 2048, 2048, 200, 256, 2048, 2048);
  trans_pad<<<dim3(9, 64), b256, 0, stream>>>(lr_x, xb, 512, 544);

  // ---- layer-1 projections
  mfma_bt<1, false, false><<<dim3(4, 32), b256, 0, stream>>>(
      xb, Wqk1, qk1b, 544, 544, 512, 544, 1, 0, 0, 0, -1, 0, -1, 4096, 1.f, nullptr);
  mfma_bt<1, false, false><<<dim3(32, 4), b256, 0, stream>>>(
      Wv1b, xb, v1b, 544, 544, 4096, 544, 1, 0, 0, 0, -1, 0, -1, 512, 1.f, nullptr);
  mfma_bt<0, false, false><<<dim3(32, 4), b256, 0, stream>>>(
      Ws1p, xb, s1p, 544, 544, 4096, 544, 1, 0, 0, 0, -1, 0, 127, 50, 1.f, nullptr);

  // ---- attention 1: expS scores (+rowsum) -> PV atomic -> gn1
  mfma_bt<1, false, true><<<dim3(32, 32, 4), b256, 0, stream>>>(
      qk1b, qk1b + 256, Pall, 512, 512, 4096, 64, 1,
      64, 64, PSTR, -1, 0, -1, 4096, sc1, r1);
  mfma_bt<2, false, false><<<dim3(32, 4, 8), b256, 0, stream>>>(
      v1b, Pall, o1p, 4096, 4096, 4096, 4096, 8,
      0, 0, 0, 7, PSTR, 127, 50, 1.f, nullptr);
  graph_norm_attn1<<<dim3(200), b256, 0, stream>>>(s1p, o1p, r1, h1nT, gn1w, gn1b, gn1ms);
  trans_pad<<<dim3(4, 64), b256, 0, stream>>>(h1nT, h1nb, 200, 256);

  // ---- layer-2 projections (8-phase): qk node-major; [v|skip] feature-major
  mfma256_8ph<1, false, false><<<dim3(16, 16), b512, 0, stream>>>(
      h1nb, Wqk2, qk2b, 256, 256, 4096, 256, 1, 0, 0, 0, -1, 0, 4096, 1.f, nullptr);
  mfma256_8ph<1, false, false><<<dim3(16, 16), b512, 0, stream>>>(
      Wcat, h1nb, vs2b, 256, 256, 4096, 256, 1, 0, 0, 0, -1, 0, 4096, 1.f, nullptr);

  // ---- attention 2: expS scores (+rowsum) -> PV partials (alias qk2b) -> gn2
  mfma256_8ph<1, false, true><<<dim3(16, 16, 4), b512, 0, stream>>>(
      qk2b, qk2b + 2048, Pall, 4096, 4096, 4096, 512, 1,
      512, 512, PSTR, -1, 0, 4096, sc2, r2);
  mfma256_8ph<1, false, false><<<dim3(16, 8, 2), b512, 0, stream>>>(
      vs2b, Pall, p2, 4096, 4096, 4096, 4096, 2,
      0, 0, (size_t)2048 * 4096, 9, PSTR, 2048, 1.f, nullptr);
  graph_norm_attn2<<<dim3(2048), b256, 0, stream>>>(
      vs2b + (size_t)2048 * 4096, p2, r2, h2b, gn2w, gn2b, gn2ms);

  // ---- out = relu(h2n . h2n^T): K-split partials (alias Pall) + reduce
  mfma256_8ph<0, false, false><<<dim3(8, 8, 4), b512, 0, stream>>>(
      h2b, h2b, g4, 4096, 4096, 2048, 4096, 4,
      0, 0, (size_t)2048 * 2048, -1, 0, 2048, 1.f, nullptr);
  add4_relu<<<dim3(4096), b256, 0, stream>>>(g4, (float*)d_out);
}